// Round 15
// baseline (153.926 us; speedup 1.0000x reference)
//
#include <hip/hip_runtime.h>
#include <hip/hip_bf16.h>
#include <cstdint>

typedef __attribute__((ext_vector_type(8))) short short8;
typedef __attribute__((ext_vector_type(4))) float f32x4;
typedef __attribute__((ext_vector_type(2))) unsigned int uint2v;
typedef unsigned short ushort_t;

#define S_LEN 2048
#define D_DIM 1024
#define NH 16
#define DK 64
#define BATCH 2
#define M_ROWS (BATCH * S_LEN)   // 4096
#define BK 32
#define NSPL 14                  // split j's: 18..31
#define MLSTR (32 * NSPL * 64)   // 28672 rows per kk bank

__device__ inline ushort_t f2bf(float f) {
    union { float f; uint32_t u; } v; v.f = f;
    uint32_t r = v.u + 0x7fffu + ((v.u >> 16) & 1u);  // RNE
    return (ushort_t)(r >> 16);
}

__device__ __forceinline__ ushort_t bfc(float f) {
    __hip_bfloat16 h = __float2bfloat16(f);          // HW cvt path
    return __builtin_bit_cast(ushort_t, h);
}

__device__ __forceinline__ float bf2f(ushort_t u) {
    return __uint_as_float(((uint32_t)u) << 16);
}

__device__ __forceinline__ float fexp2(float x) {
#if __has_builtin(__builtin_amdgcn_exp2f)
    return __builtin_amdgcn_exp2f(x);
#else
    return exp2f(x);
#endif
}
__device__ __forceinline__ float frcp(float x) {
#if __has_builtin(__builtin_amdgcn_rcpf)
    return __builtin_amdgcn_rcpf(x);
#else
    return 1.0f / x;
#endif
}

__device__ __forceinline__ void glds16(const ushort_t* g, ushort_t* l) {
    __builtin_amdgcn_global_load_lds(
        (const __attribute__((address_space(1))) uint32_t*)g,
        (__attribute__((address_space(3))) uint32_t*)l,
        16, 0, 0);
}

#if __has_builtin(__builtin_amdgcn_permlane16_swap) && __has_builtin(__builtin_amdgcn_permlane32_swap)
#define HAS_PLSWAP 1
#else
#define HAS_PLSWAP 0
#endif

// cross-lane reduce over the 4 16-lane groups (lanes l, l^16, l^32, l^48)
__device__ __forceinline__ float red_max4(float x) {
#if HAS_PLSWAP
    uint2v a = __builtin_amdgcn_permlane16_swap(__float_as_uint(x), __float_as_uint(x), false, false);
    float y = fmaxf(__uint_as_float(a.x), __uint_as_float(a.y));
    uint2v b = __builtin_amdgcn_permlane32_swap(__float_as_uint(y), __float_as_uint(y), false, false);
    return fmaxf(__uint_as_float(b.x), __uint_as_float(b.y));
#else
    x = fmaxf(x, __shfl_xor(x, 16));
    return fmaxf(x, __shfl_xor(x, 32));
#endif
}
__device__ __forceinline__ float red_sum4(float x) {
#if HAS_PLSWAP
    uint2v a = __builtin_amdgcn_permlane16_swap(__float_as_uint(x), __float_as_uint(x), false, false);
    float y = __uint_as_float(a.x) + __uint_as_float(a.y);
    uint2v b = __builtin_amdgcn_permlane32_swap(__float_as_uint(y), __float_as_uint(y), false, false);
    return __uint_as_float(b.x) + __uint_as_float(b.y);
#else
    x += __shfl_xor(x, 16);
    return x + __shfl_xor(x, 32);
#endif
}

// T12 route: build PV A-frag words F[0..3] for k-slice ks from packed P words
__device__ __forceinline__ void route_p(const uint32_t wp[4][2], int ks, int lane, uint32_t F[4]) {
#if HAS_PLSWAP
    uint32_t U0 = wp[2 * ks][0],     U1 = wp[2 * ks][1];
    uint32_t V0 = wp[2 * ks + 1][0], V1 = wp[2 * ks + 1][1];
    uint2v t, pa0, pa1, pb0, pb1;
    t = __builtin_amdgcn_permlane32_swap(U0, U0, false, false);
    pa0 = __builtin_amdgcn_permlane16_swap(U0, t.y, false, false);
    t = __builtin_amdgcn_permlane32_swap(U1, U1, false, false);
    pa1 = __builtin_amdgcn_permlane16_swap(U1, t.y, false, false);
    t = __builtin_amdgcn_permlane32_swap(V0, V0, false, false);
    pb0 = __builtin_amdgcn_permlane16_swap(t.x, V0, false, false);
    t = __builtin_amdgcn_permlane32_swap(V1, V1, false, false);
    pb1 = __builtin_amdgcn_permlane16_swap(t.x, V1, false, false);
    bool lo = lane < 32;
    F[0] = lo ? pa0.x : pb0.x;
    F[1] = lo ? pa1.x : pb1.x;
    F[2] = lo ? pa0.y : pb0.y;
    F[3] = lo ? pa1.y : pb1.y;
#else
    int q = lane & 15, g = lane >> 4;
#pragma unroll
    for (int m = 0; m < 4; m++) {
        int src = 16 * (2 * (g & 1) + (m >> 1)) + q;
        uint32_t xa = (uint32_t)__shfl((int)wp[2 * ks][m & 1], src);
        uint32_t xb = (uint32_t)__shfl((int)wp[2 * ks + 1][m & 1], src);
        F[m] = (g < 2) ? xa : xb;
    }
#endif
}

// ---------------- fp32 -> bf16 convert (vectorized) ----------------
__global__ void cvt_bf16(const float* __restrict__ in, ushort_t* __restrict__ out, int n4) {
    int i = blockIdx.x * blockDim.x + threadIdx.x;
    int stride = gridDim.x * blockDim.x;
    for (int idx = i; idx < n4; idx += stride) {
        float4 v = ((const float4*)in)[idx];
        ushort4 o;
        o.x = f2bf(v.x); o.y = f2bf(v.y); o.z = f2bf(v.z); o.w = f2bf(v.w);
        ((ushort4*)out)[idx] = o;
    }
}

// fused convert of Wq,Wk,Wv into one [3072,1024] bf16 buffer
__global__ void cvt_w3(const float* __restrict__ wq, const float* __restrict__ wk,
                       const float* __restrict__ wv, ushort_t* __restrict__ wqkv) {
    const int seg = (D_DIM * D_DIM) / 4;   // 2^18
    int i = blockIdx.x * blockDim.x + threadIdx.x;
    int stride = gridDim.x * blockDim.x;
    for (int idx = i; idx < 3 * seg; idx += stride) {
        int sel = idx >> 18;
        int id = idx & (seg - 1);
        const float* src = sel == 0 ? wq : (sel == 1 ? wk : wv);
        float4 v = ((const float4*)src)[id];
        ushort4 o;
        o.x = f2bf(v.x); o.y = f2bf(v.y); o.z = f2bf(v.z); o.w = f2bf(v.w);
        ((ushort4*)wqkv)[sel * seg + id] = o;
    }
}

// ---------------- GEMM: C = A[M,K] * Bw[N,K]^T + bias ----------------
// T1 XCD remap + single-barrier dbuf staging. NEW: swapped-operand MFMA
// (mfma(bf,af): reg-dim = N, lane-dim = M) for MODE 2 and MODE 3 Q/K so the
// epilogue packs 4 consecutive N-elements per store (16 stores vs 64).
// V^T output keeps the unswapped path (its packing is along M).
template<int MODE, int BMt, int BNt>
__global__ __launch_bounds__(256, 3) void gemm_bt(const ushort_t* __restrict__ A,
                                                  const ushort_t* __restrict__ Bw,
                                                  const float* __restrict__ b0,
                                                  const float* __restrict__ b1,
                                                  const float* __restrict__ b2,
                                                  void* __restrict__ C0,
                                                  void* __restrict__ C1,
                                                  void* __restrict__ C2,
                                                  int M, int N, int K) {
    constexpr int FM = BMt / 32, FN = BNt / 32;
    constexpr int ACH = BMt / 64, BCH = BNt / 64;
    __shared__ ushort_t As[2][BMt * BK];
    __shared__ ushort_t Bs[2][BNt * BK];
    int tid = threadIdx.x;
    int lane = tid & 63;
    int w = tid >> 6;
    int wr = w >> 1, wc = w & 1;
    int nwg = gridDim.x;
    int bx = (blockIdx.x & 7) * (nwg >> 3) + (blockIdx.x >> 3);
    int ntile = N / BNt;
    int m0 = (bx / ntile) * BMt;
    int n0 = (bx % ntile) * BNt;
    int lr = lane & 15;
    int lk = (lane >> 4) * 8;
    int srow = lane >> 2;            // 0..15
    int scol = (lane & 3) * 8;
    int sel = n0 >> 10;              // block-uniform (MODE 3 routing)
    bool swp = (MODE == 2) || (sel < 2);

    auto stage = [&](int b, int kt) {
#pragma unroll
        for (int c = 0; c < ACH; c++)
            glds16(&A[(size_t)(m0 + w * (BMt / 4) + c * 16 + srow) * K + kt + scol],
                   &As[b][(w * (BMt / 4) + c * 16) * BK]);
#pragma unroll
        for (int c = 0; c < BCH; c++)
            glds16(&Bw[(size_t)(n0 + w * (BNt / 4) + c * 16 + srow) * K + kt + scol],
                   &Bs[b][(w * (BNt / 4) + c * 16) * BK]);
    };

    f32x4 acc[FM][FN] = {};

    stage(0, 0);
    __syncthreads();
    int cur = 0;
    for (int kt = 0; kt < K; kt += BK) {
        if (kt + BK < K) stage(cur ^ 1, kt + BK);

        short8 af[FM], bf[FN];
#pragma unroll
        for (int f = 0; f < FM; f++)
            af[f] = *(const short8*)&As[cur][(wr * (BMt / 2) + f * 16 + lr) * BK + lk];
#pragma unroll
        for (int f = 0; f < FN; f++)
            bf[f] = *(const short8*)&Bs[cur][(wc * (BNt / 2) + f * 16 + lr) * BK + lk];
        if (swp) {
#pragma unroll
            for (int i = 0; i < FM; i++)
#pragma unroll
                for (int j = 0; j < FN; j++)
                    acc[i][j] = __builtin_amdgcn_mfma_f32_16x16x32_bf16(bf[j], af[i], acc[i][j], 0, 0, 0);
        } else {
#pragma unroll
            for (int i = 0; i < FM; i++)
#pragma unroll
                for (int j = 0; j < FN; j++)
                    acc[i][j] = __builtin_amdgcn_mfma_f32_16x16x32_bf16(af[i], bf[j], acc[i][j], 0, 0, 0);
        }

        __syncthreads();
        cur ^= 1;
    }

    int r0 = (lane >> 4) * 4;
    if (MODE == 2) {
        // swapped: m = ...+lr (lane), n = ...+r0+r (reg) -> float4 stores
#pragma unroll
        for (int j = 0; j < FN; j++) {
            int nc0 = n0 + wc * (BNt / 2) + j * 16 + r0;
            float4 bv = *(const float4*)&b0[nc0];
#pragma unroll
            for (int i = 0; i < FM; i++) {
                int mm = m0 + wr * (BMt / 2) + i * 16 + lr;
                float4 v;
                v.x = acc[i][j][0] + bv.x;
                v.y = acc[i][j][1] + bv.y;
                v.z = acc[i][j][2] + bv.z;
                v.w = acc[i][j][3] + bv.w;
                *(float4*)&((float*)C0)[(size_t)mm * N + nc0] = v;
            }
        }
    } else if (sel < 2) {
        // swapped Q/K: [b,h,s,dk] with 4 consecutive dk -> ushort4 stores
        ushort_t* Co = (ushort_t*)(sel == 0 ? C0 : C1);
        const float* bp = sel == 0 ? b0 : b1;
#pragma unroll
        for (int j = 0; j < FN; j++) {
            int nc0 = (n0 + wc * (BNt / 2) + j * 16 + r0) & 1023;
            int hh = nc0 >> 6, dk0 = nc0 & 63;
            float4 bv = *(const float4*)&bp[nc0];
#pragma unroll
            for (int i = 0; i < FM; i++) {
                int mm = m0 + wr * (BMt / 2) + i * 16 + lr;
                int bb = mm >> 11, ss = mm & 2047;
                ushort4 pk;
                pk.x = f2bf(acc[i][j][0] + bv.x);
                pk.y = f2bf(acc[i][j][1] + bv.y);
                pk.z = f2bf(acc[i][j][2] + bv.z);
                pk.w = f2bf(acc[i][j][3] + bv.w);
                size_t idx = ((size_t)(bb * NH + hh) * S_LEN + ss) * DK + dk0;
                *(ushort4*)&Co[idx] = pk;
            }
        }
    } else {
        // unswapped V^T: [b,h,dk,s] packing 4 consecutive s (reg = M)
        ushort_t* Co = (ushort_t*)C2;
        const float* bp = b2;
#pragma unroll
        for (int j = 0; j < FN; j++) {
            int ncol = n0 + wc * (BNt / 2) + j * 16 + lr;
            int nc = ncol & 1023;
            float bv = bp[nc];
            int hh = nc >> 6, dk = nc & 63;
#pragma unroll
            for (int i = 0; i < FM; i++) {
                int mbase = m0 + wr * (BMt / 2) + i * 16 + r0;
                int bb = mbase >> 11, ss = mbase & 2047;
                ushort4 pk;
                pk.x = f2bf(acc[i][j][0] + bv);
                pk.y = f2bf(acc[i][j][1] + bv);
                pk.z = f2bf(acc[i][j][2] + bv);
                pk.w = f2bf(acc[i][j][3] + bv);
                size_t idx = ((size_t)(bb * NH + hh) * DK + dk) * S_LEN + ss;
                *(ushort4*)&Co[idx] = pk;
            }
        }
    }
}

// ---------------- Flash attention (causal, equal-length chunks) ----------------
// Grid (bh=32, y=40) = 1280 blocks = 5/CU. Chunk lengths 7..18 (was 7..24):
// j=0..12 bundled in pairs (two full q-tile passes per block), j=13..17
// single full blocks, j=18..31 halved. Residency classes (y%8) each sum
// exactly 66 tile-units. KT encoding: 0/1 = split chunk, 9 = full single,
// 10+jb = bundle {JT, jb}. Inner machinery = round-13 verified (unchanged).
#define CSC 0.1803368801f   // 0.125 * log2(e)

__device__ const unsigned char JTAB[40] = {
    17,16,15,30,31,31,13,27,
    24,18,18,19,19,20,26,28,
    12,14,28,29,29,30,27,25,
    11,10, 9, 8, 7,25,23,26,
     6,20,21,21,22,22,23,24};
__device__ const unsigned char KTAB[40] = {
     9, 9, 9, 0, 0, 1, 9, 1,
     0, 1, 0, 0, 1, 1, 0, 1,
    10, 9, 0, 0, 1, 1, 0, 1,
    11,12,13,14,15, 0, 0, 1,
     9, 0, 0, 1, 1, 0, 1, 1};

__global__ __launch_bounds__(256, 5) void attn_fwd(const ushort_t* __restrict__ Q,
                                                   const ushort_t* __restrict__ K,
                                                   const ushort_t* __restrict__ Vt,
                                                   ushort_t* __restrict__ Oa,
                                                   float2* __restrict__ ml,
                                                   float* __restrict__ Pd) {
    __shared__ ushort_t Ks[2][64 * 64];
    __shared__ ushort_t Vs[2][64 * 64];

    int tid = threadIdx.x;
    int lane = tid & 63;
    int w = tid >> 6;
    int bh = blockIdx.x;           // 0..31
    int yy = blockIdx.y;           // 0..39
    int JT = JTAB[yy];
    int KT = KTAB[yy];
    int nseg = (KT >= 10) ? 2 : 1;
    size_t base = (size_t)bh * S_LEN * DK;

    int lr = lane & 15;
    int lk = (lane >> 4) * 8;
    int g16 = (lane >> 4) * 16;
    int r0 = (lane >> 4) * 4;
    int wq = w * 16 + lr;

    // Hoisted LDS read bases (round-13 algebra: (n*16+lr)&7 == lr&7)
    int swb = (lr & 7) << 4;
    int swLo = (lr * 128 + (g16 ^ swb)) >> 1;
    int swHi = (lr * 128 + ((64 + g16) ^ swb)) >> 1;

    int sr = tid >> 3;            // 0..31
    int scb = (tid & 7) * 16;
    int wOff = (sr * 128 + (scb ^ ((sr & 7) << 4))) >> 1;

    const ushort_t* kBase = K  + base + (size_t)sr * DK + ((tid & 7) * 8);
    const ushort_t* vBase = Vt + base + (size_t)sr * S_LEN + ((tid & 7) * 8);
    int b = bh >> 4, h = bh & 15;

    for (int seg = 0; seg < nseg; ++seg) {
        int j = (seg == 0) ? JT : (KT - 10);
        int kk = (KT <= 1) ? KT : 9;            // splits only when KT is 0/1
        int nt = j + 1;
        int half = (nt + 1) >> 1;
        int t0 = (kk == 1) ? half : 0;
        int t1 = (kk == 0) ? half : nt;
        int cnt = t1 - t0;
        int off = yy % cnt;
        int q0 = j * 64;

        short8 qf0 = *(const short8*)&Q[base + (size_t)(q0 + wq) * DK + lk];
        short8 qf1 = *(const short8*)&Q[base + (size_t)(q0 + wq) * DK + 32 + lk];

        f32x4 o[4] = {};
        float mrowL = -1e30f, lrow = 0.f;

        // prologue: stage first (staggered) tile into buf 0
        int tf = t0 + off;
        {
            const ushort_t* kp = kBase + (size_t)tf * (64 * DK);
            const ushort_t* vp = vBase + (size_t)tf * 64;
            *(uint4*)&Ks[0][wOff]        = *(const uint4*)kp;
            *(uint4*)&Ks[0][wOff + 2048] = *(const uint4*)(kp + 32 * DK);
            *(uint4*)&Vs[0][wOff]        = *(const uint4*)vp;
            *(uint4*)&Vs[0][wOff + 2048] = *(const uint4*)(vp + 32 * S_LEN);
        }
        __syncthreads();

        int t = tf;
        int tpre = (tf == t1 - 1) ? t0 : tf + 1;
        const ushort_t* kPre = kBase + (size_t)tpre * (64 * DK);
        const ushort_t* vPre = vBase + (size_t)tpre * 64;

        int cur = 0;
        for (int s = 0; s < cnt; ++s) {
            bool last = (s == cnt - 1);
            bool diag = (t == j);
            uint4 kr0, kr1, vr0, vr1;
            if (!last) {
                kr0 = *(const uint4*)kPre;
                kr1 = *(const uint4*)(kPre + 32 * DK);
                vr0 = *(const uint4*)vPre;
                vr1 = *(const uint4*)(vPre + 32 * S_LEN);
            }

            f32x4 st[4] = {};
            __builtin_amdgcn_s_setprio(1);
#pragma unroll
            for (int n = 0; n < 4; n++) {
                if (!diag || n <= w) {
                    short8 kf0 = *(const short8*)&Ks[cur][swLo + n * 1024];
                    short8 kf1 = *(const short8*)&Ks[cur][swHi + n * 1024];
                    st[n] = __builtin_amdgcn_mfma_f32_16x16x32_bf16(kf0, qf0, st[n], 0, 0, 0);
                    st[n] = __builtin_amdgcn_mfma_f32_16x16x32_bf16(kf1, qf1, st[n], 0, 0, 0);
                }
            }
            __builtin_amdgcn_s_setprio(0);

            if (diag) {
#pragma unroll
                for (int n = 0; n < 4; n++)
#pragma unroll
                    for (int i = 0; i < 4; i++)
                        if (16 * n + r0 + i > wq) st[n][i] = -1e30f;
            }

            float m0 = fmaxf(fmaxf(fmaxf(st[0][0], st[0][1]), st[0][2]), st[0][3]);
            float m1 = fmaxf(fmaxf(fmaxf(st[1][0], st[1][1]), st[1][2]), st[1][3]);
            float m2 = fmaxf(fmaxf(fmaxf(st[2][0], st[2][1]), st[2][2]), st[2][3]);
            float m3 = fmaxf(fmaxf(fmaxf(st[3][0], st[3][1]), st[3][2]), st[3][3]);
            float mx = fmaxf(fmaxf(fmaxf(m0, m1), m2), m3);
            float mxL = red_max4(mx) * CSC;

            bool skip = __all(mxL <= mrowL + 8.0f);   // T13 defer-max
            float corr = 1.0f;
            float mnewL = mrowL;
            if (!skip) {
                mnewL = fmaxf(mrowL, mxL);
                corr = fexp2(mrowL - mnewL);
                mrowL = mnewL;
            }

            float psum = 0.f;
            uint32_t wp[4][2];
#pragma unroll
            for (int n = 0; n < 4; n++) {
#pragma unroll
                for (int i = 0; i < 4; i++) {
                    float p = fexp2(fmaf(st[n][i], CSC, -mnewL));
                    st[n][i] = p;
                    psum += p;
                }
                wp[n][0] = (uint32_t)bfc(st[n][0]) | ((uint32_t)bfc(st[n][1]) << 16);
                wp[n][1] = (uint32_t)bfc(st[n][2]) | ((uint32_t)bfc(st[n][3]) << 16);
            }
            psum = red_sum4(psum);

            if (skip) {
                lrow += psum;
            } else {
                lrow = lrow * corr + psum;
                float cb[4];
#pragma unroll
                for (int i = 0; i < 4; i++) cb[i] = __shfl(corr, r0 + i);
#pragma unroll
                for (int d = 0; d < 4; d++)
#pragma unroll
                    for (int i = 0; i < 4; i++) o[d][i] *= cb[i];
            }

#pragma unroll
            for (int ks = 0; ks < 2; ks++) {
                if (diag && 32 * ks > w * 16 + 15) continue;
                uint32_t F[4];
                route_p(wp, ks, lane, F);
                union { uint32_t u[4]; short8 s; } pu;
                pu.u[0] = F[0]; pu.u[1] = F[1]; pu.u[2] = F[2]; pu.u[3] = F[3];
                short8 pf = pu.s;
                int vb = (ks ? swHi : swLo);
                __builtin_amdgcn_s_setprio(1);
#pragma unroll
                for (int d = 0; d < 4; d++) {
                    short8 vf = *(const short8*)&Vs[cur][vb + d * 1024];
                    o[d] = __builtin_amdgcn_mfma_f32_16x16x32_bf16(pf, vf, o[d], 0, 0, 0);
                }
                __builtin_amdgcn_s_setprio(0);
            }

            if (!last) {
                *(uint4*)&Ks[cur ^ 1][wOff]        = kr0;
                *(uint4*)&Ks[cur ^ 1][wOff + 2048] = kr1;
                *(uint4*)&Vs[cur ^ 1][wOff]        = vr0;
                *(uint4*)&Vs[cur ^ 1][wOff + 2048] = vr1;
            }
            __syncthreads();
            cur ^= 1;

            t = tpre;
            bool wrap = (tpre == t1 - 1);
            tpre = wrap ? t0 : tpre + 1;
            kPre += wrap ? -(ptrdiff_t)(cnt - 1) * (64 * DK) : (ptrdiff_t)(64 * DK);
            vPre += wrap ? -(ptrdiff_t)(cnt - 1) * 64 : (ptrdiff_t)64;
        }

        // segment epilogue
        if (kk == 9) {
            float lb[4];
#pragma unroll
            for (int i = 0; i < 4; i++) lb[i] = frcp(__shfl(lrow, r0 + i));
#pragma unroll
            for (int d = 0; d < 4; d++)
#pragma unroll
                for (int i = 0; i < 4; i++) {
                    int qq = q0 + w * 16 + r0 + i;
                    int dk = d * 16 + lr;
                    size_t idx = ((size_t)(b * S_LEN + qq)) * D_DIM + h * DK + dk;
                    Oa[idx] = bfc(o[d][i] * lb[i]);
                }
        } else {
            int jj = j - 18;               // split j's are 18..31
            if (kk == 0) {
#pragma unroll
                for (int d = 0; d < 4; d++)
#pragma unroll
                    for (int i = 0; i < 4; i++) {
                        int qq = q0 + w * 16 + r0 + i;
                        int dk = d * 16 + lr;
                        size_t idx = ((size_t)(b * S_LEN + qq)) * D_DIM + h * DK + dk;
                        Oa[idx] = bfc(o[d][i]);
                    }
            } else {
#pragma unroll
                for (int d = 0; d < 4; d++)
#pragma unroll
                    for (int i = 0; i < 4; i++) {
                        int rloc = w * 16 + r0 + i;
                        Pd[((size_t)(bh * NSPL + jj) * 64 + rloc) * 64 + d * 16 + lr] = o[d][i];
                    }
            }
            if (lane < 16) {
                int row = w * 16 + lane;
                ml[(size_t)kk * MLSTR + (bh * NSPL + jj) * 64 + row] = make_float2(mrowL, lrow);
            }
        }
    }
}

// ---------------- merge of split-tile partials (j = 18..31) ----------------
__global__ __launch_bounds__(256) void attn_merge(const float2* __restrict__ ml,
                                                  const float* __restrict__ Pd,
                                                  ushort_t* __restrict__ Oa) {
    int bh = blockIdx.x;           // 0..31
    int jj = blockIdx.y;           // 0..13 -> j = jj+18
    int tid = threadIdx.x;
    int r = tid >> 2;              // row 0..63
    int q = (tid & 3) * 16;        // dk start
    int b = bh >> 4, h = bh & 15;
    int row = (jj + 18) * 64 + r;
    float2 a = ml[(bh * NSPL + jj) * 64 + r];
    float2 c = ml[MLSTR + (bh * NSPL + jj) * 64 + r];
    float M = fmaxf(a.x, c.x);
    float w0 = fexp2(a.x - M), w1 = fexp2(c.x - M);
    float rc = frcp(a.y * w0 + c.y * w1);
    size_t ob = ((size_t)(b * S_LEN + row)) * D_DIM + h * DK + q;
    const float* p1 = &Pd[((size_t)(bh * NSPL + jj) * 64 + r) * 64 + q];
#pragma unroll
    for (int i = 0; i < 4; i++) {
        ushort4 o0 = *(const ushort4*)&Oa[ob + i * 4];
        float4 o1 = *(const float4*)&p1[i * 4];
        ushort4 res;
        res.x = bfc((bf2f(o0.x) * w0 + o1.x * w1) * rc);
        res.y = bfc((bf2f(o0.y) * w0 + o1.y * w1) * rc);
        res.z = bfc((bf2f(o0.z) * w0 + o1.z * w1) * rc);
        res.w = bfc((bf2f(o0.w) * w0 + o1.w * w1) * rc);
        *(ushort4*)&Oa[ob + i * 4] = res;
    }
}

// ---------------- launch ----------------
extern "C" void kernel_launch(void* const* d_in, const int* in_sizes, int n_in,
                              void* d_out, int out_size, void* d_ws, size_t ws_size,
                              hipStream_t stream) {
    const float* X  = (const float*)d_in[0];
    const float* Wq = (const float*)d_in[1];
    const float* bq = (const float*)d_in[2];
    const float* Wk = (const float*)d_in[3];
    const float* bk = (const float*)d_in[4];
    const float* Wv = (const float*)d_in[5];
    const float* bv = (const float*)d_in[6];
    const float* Wo = (const float*)d_in[7];
    const float* bo = (const float*)d_in[8];
    float* out = (float*)d_out;

    char* ws = (char*)d_ws;
    ushort_t* Xb    = (ushort_t*)ws;                        // 8 MiB [M,D] bf16 (later: attn out)
    ushort_t* Wqkvb = (ushort_t*)(ws + (8u  << 20));        // 6 MiB; dead after QKV gemm
    float2*   mlbuf = (float2*)(ws + (8u  << 20));          // 448 KiB (over dead Wqkvb)
    ushort_t* Qb    = (ushort_t*)(ws + (14u << 20));        // 8 MiB [b,h,s,dk]
    ushort_t* Kb    = (ushort_t*)(ws + (22u << 20));        // 8 MiB [b,h,s,dk]
    ushort_t* Vtb   = (ushort_t*)(ws + (30u << 20));        // 8 MiB [b,h,dk,s]
    ushort_t* Wob   = Wqkvb;                                // reuse after merge
    ushort_t* Ab    = Xb;                                   // attn out reuses X slot
    float*    Pd    = out;                                  // chunk1 partials scratch (dead until Wo gemm)

    const int M = M_ROWS;
    int nX4 = (M * D_DIM) / 4;
    int nW4 = (D_DIM * D_DIM) / 4;

    cvt_bf16<<<2048, 256, 0, stream>>>(X, Xb, nX4);
    cvt_w3<<<2048, 256, 0, stream>>>(Wq, Wk, Wv, Wqkvb);

    // fused QKV: 32 x 24 = 768 blocks (3/CU)
    gemm_bt<3, 128, 128><<<dim3((M / 128) * (3072 / 128)), 256, 0, stream>>>(
        Xb, Wqkvb, bq, bk, bv, Qb, Kb, Vtb, M, 3072, D_DIM);

    // attn: 32 x 40 = 1280 chunk-blocks = 5/CU, lengths 7..18, class sums 66
    dim3 agrid(BATCH * NH, 40);
    attn_fwd<<<agrid, 256, 0, stream>>>(Qb, Kb, Vtb, Ab, mlbuf, Pd);

    // merge split-tile partials (j=18..31)
    attn_merge<<<dim3(BATCH * NH, NSPL), 256, 0, stream>>>(mlbuf, Pd, Ab);

    cvt_bf16<<<2048, 256, 0, stream>>>(Wo, Wob, nW4);   // after merge (overlays mlbuf)

    // Wo gemm: 64x128 tiles -> 512 blocks (2/CU); overwrites all of d_out
    gemm_bt<2, 64, 128><<<dim3((M / 64) * (D_DIM / 128)), 256, 0, stream>>>(
        Ab, Wob, bo, bo, bo, out, out, out, M, D_DIM, D_DIM);
}

// Round 16
// 122.047 us; speedup vs baseline: 1.2612x; 1.2612x over previous
//
#include <hip/hip_runtime.h>
#include <hip/hip_bf16.h>
#include <cstdint>

typedef __attribute__((ext_vector_type(8))) short short8;
typedef __attribute__((ext_vector_type(4))) float f32x4;
typedef __attribute__((ext_vector_type(2))) unsigned int uint2v;
typedef unsigned short ushort_t;

#define S_LEN 2048
#define D_DIM 1024
#define NH 16
#define DK 64
#define BATCH 2
#define M_ROWS (BATCH * S_LEN)   // 4096
#define BK 32
#define NSPL 14                  // split j's: 18..31
#define MLSTR (32 * NSPL * 64)   // rows per kk bank

__device__ inline ushort_t f2bf(float f) {
    union { float f; uint32_t u; } v; v.f = f;
    uint32_t r = v.u + 0x7fffu + ((v.u >> 16) & 1u);  // RNE
    return (ushort_t)(r >> 16);
}

__device__ __forceinline__ ushort_t bfc(float f) {
    __hip_bfloat16 h = __float2bfloat16(f);          // HW cvt path
    return __builtin_bit_cast(ushort_t, h);
}

__device__ __forceinline__ float bf2f(ushort_t u) {
    return __uint_as_float(((uint32_t)u) << 16);
}

__device__ __forceinline__ float fexp2(float x) {
#if __has_builtin(__builtin_amdgcn_exp2f)
    return __builtin_amdgcn_exp2f(x);
#else
    return exp2f(x);
#endif
}
__device__ __forceinline__ float frcp(float x) {
#if __has_builtin(__builtin_amdgcn_rcpf)
    return __builtin_amdgcn_rcpf(x);
#else
    return 1.0f / x;
#endif
}

__device__ __forceinline__ void glds16(const ushort_t* g, ushort_t* l) {
    __builtin_amdgcn_global_load_lds(
        (const __attribute__((address_space(1))) uint32_t*)g,
        (__attribute__((address_space(3))) uint32_t*)l,
        16, 0, 0);
}

#if __has_builtin(__builtin_amdgcn_permlane16_swap) && __has_builtin(__builtin_amdgcn_permlane32_swap)
#define HAS_PLSWAP 1
#else
#define HAS_PLSWAP 0
#endif

// cross-lane reduce over the 4 16-lane groups (lanes l, l^16, l^32, l^48)
__device__ __forceinline__ float red_max4(float x) {
#if HAS_PLSWAP
    uint2v a = __builtin_amdgcn_permlane16_swap(__float_as_uint(x), __float_as_uint(x), false, false);
    float y = fmaxf(__uint_as_float(a.x), __uint_as_float(a.y));
    uint2v b = __builtin_amdgcn_permlane32_swap(__float_as_uint(y), __float_as_uint(y), false, false);
    return fmaxf(__uint_as_float(b.x), __uint_as_float(b.y));
#else
    x = fmaxf(x, __shfl_xor(x, 16));
    return fmaxf(x, __shfl_xor(x, 32));
#endif
}
__device__ __forceinline__ float red_sum4(float x) {
#if HAS_PLSWAP
    uint2v a = __builtin_amdgcn_permlane16_swap(__float_as_uint(x), __float_as_uint(x), false, false);
    float y = __uint_as_float(a.x) + __uint_as_float(a.y);
    uint2v b = __builtin_amdgcn_permlane32_swap(__float_as_uint(y), __float_as_uint(y), false, false);
    return __uint_as_float(b.x) + __uint_as_float(b.y);
#else
    x += __shfl_xor(x, 16);
    return x + __shfl_xor(x, 32);
#endif
}

// T12 route: build PV A-frag words F[0..3] for k-slice ks from packed P words
__device__ __forceinline__ void route_p(const uint32_t wp[4][2], int ks, int lane, uint32_t F[4]) {
#if HAS_PLSWAP
    uint32_t U0 = wp[2 * ks][0],     U1 = wp[2 * ks][1];
    uint32_t V0 = wp[2 * ks + 1][0], V1 = wp[2 * ks + 1][1];
    uint2v t, pa0, pa1, pb0, pb1;
    t = __builtin_amdgcn_permlane32_swap(U0, U0, false, false);
    pa0 = __builtin_amdgcn_permlane16_swap(U0, t.y, false, false);
    t = __builtin_amdgcn_permlane32_swap(U1, U1, false, false);
    pa1 = __builtin_amdgcn_permlane16_swap(U1, t.y, false, false);
    t = __builtin_amdgcn_permlane32_swap(V0, V0, false, false);
    pb0 = __builtin_amdgcn_permlane16_swap(t.x, V0, false, false);
    t = __builtin_amdgcn_permlane32_swap(V1, V1, false, false);
    pb1 = __builtin_amdgcn_permlane16_swap(t.x, V1, false, false);
    bool lo = lane < 32;
    F[0] = lo ? pa0.x : pb0.x;
    F[1] = lo ? pa1.x : pb1.x;
    F[2] = lo ? pa0.y : pb0.y;
    F[3] = lo ? pa1.y : pb1.y;
#else
    int q = lane & 15, g = lane >> 4;
#pragma unroll
    for (int m = 0; m < 4; m++) {
        int src = 16 * (2 * (g & 1) + (m >> 1)) + q;
        uint32_t xa = (uint32_t)__shfl((int)wp[2 * ks][m & 1], src);
        uint32_t xb = (uint32_t)__shfl((int)wp[2 * ks + 1][m & 1], src);
        F[m] = (g < 2) ? xa : xb;
    }
#endif
}

// ---------------- fp32 -> bf16 convert (vectorized) ----------------
__global__ void cvt_bf16(const float* __restrict__ in, ushort_t* __restrict__ out, int n4) {
    int i = blockIdx.x * blockDim.x + threadIdx.x;
    int stride = gridDim.x * blockDim.x;
    for (int idx = i; idx < n4; idx += stride) {
        float4 v = ((const float4*)in)[idx];
        ushort4 o;
        o.x = f2bf(v.x); o.y = f2bf(v.y); o.z = f2bf(v.z); o.w = f2bf(v.w);
        ((ushort4*)out)[idx] = o;
    }
}

// fused convert of Wq,Wk,Wv into one [3072,1024] bf16 buffer
__global__ void cvt_w3(const float* __restrict__ wq, const float* __restrict__ wk,
                       const float* __restrict__ wv, ushort_t* __restrict__ wqkv) {
    const int seg = (D_DIM * D_DIM) / 4;   // 2^18
    int i = blockIdx.x * blockDim.x + threadIdx.x;
    int stride = gridDim.x * blockDim.x;
    for (int idx = i; idx < 3 * seg; idx += stride) {
        int sel = idx >> 18;
        int id = idx & (seg - 1);
        const float* src = sel == 0 ? wq : (sel == 1 ? wk : wv);
        float4 v = ((const float4*)src)[id];
        ushort4 o;
        o.x = f2bf(v.x); o.y = f2bf(v.y); o.z = f2bf(v.z); o.w = f2bf(v.w);
        ((ushort4*)wqkv)[sel * seg + id] = o;
    }
}

// ---------------- GEMM: C = A[M,K] * Bw[N,K]^T + bias ----------------
// ROUND-13 VERIFIED VERSION (reverted: no operand swap, no runtime branch
// in the K-loop). T1 XCD remap + single-barrier dbuf staging.
template<int MODE, int BMt, int BNt>
__global__ __launch_bounds__(256, 3) void gemm_bt(const ushort_t* __restrict__ A,
                                                  const ushort_t* __restrict__ Bw,
                                                  const float* __restrict__ b0,
                                                  const float* __restrict__ b1,
                                                  const float* __restrict__ b2,
                                                  void* __restrict__ C0,
                                                  void* __restrict__ C1,
                                                  void* __restrict__ C2,
                                                  int M, int N, int K) {
    constexpr int FM = BMt / 32, FN = BNt / 32;
    constexpr int ACH = BMt / 64, BCH = BNt / 64;
    __shared__ ushort_t As[2][BMt * BK];
    __shared__ ushort_t Bs[2][BNt * BK];
    int tid = threadIdx.x;
    int lane = tid & 63;
    int w = tid >> 6;
    int wr = w >> 1, wc = w & 1;
    int nwg = gridDim.x;
    int bx = (blockIdx.x & 7) * (nwg >> 3) + (blockIdx.x >> 3);
    int ntile = N / BNt;
    int m0 = (bx / ntile) * BMt;
    int n0 = (bx % ntile) * BNt;
    int lr = lane & 15;
    int lk = (lane >> 4) * 8;
    int srow = lane >> 2;            // 0..15
    int scol = (lane & 3) * 8;

    auto stage = [&](int b, int kt) {
#pragma unroll
        for (int c = 0; c < ACH; c++)
            glds16(&A[(size_t)(m0 + w * (BMt / 4) + c * 16 + srow) * K + kt + scol],
                   &As[b][(w * (BMt / 4) + c * 16) * BK]);
#pragma unroll
        for (int c = 0; c < BCH; c++)
            glds16(&Bw[(size_t)(n0 + w * (BNt / 4) + c * 16 + srow) * K + kt + scol],
                   &Bs[b][(w * (BNt / 4) + c * 16) * BK]);
    };

    f32x4 acc[FM][FN] = {};

    stage(0, 0);
    __syncthreads();                 // drain prologue glds
    int cur = 0;
    for (int kt = 0; kt < K; kt += BK) {
        if (kt + BK < K) stage(cur ^ 1, kt + BK);   // next tile in flight

        short8 af[FM], bf[FN];
#pragma unroll
        for (int f = 0; f < FM; f++)
            af[f] = *(const short8*)&As[cur][(wr * (BMt / 2) + f * 16 + lr) * BK + lk];
#pragma unroll
        for (int f = 0; f < FN; f++)
            bf[f] = *(const short8*)&Bs[cur][(wc * (BNt / 2) + f * 16 + lr) * BK + lk];
#pragma unroll
        for (int i = 0; i < FM; i++)
#pragma unroll
            for (int j = 0; j < FN; j++)
                acc[i][j] = __builtin_amdgcn_mfma_f32_16x16x32_bf16(af[i], bf[j], acc[i][j], 0, 0, 0);

        __syncthreads();             // drains this iter's glds + ds_reads
        cur ^= 1;
    }

    int r0 = (lane >> 4) * 4;
#pragma unroll
    for (int j = 0; j < FN; j++) {
        int ncol = n0 + wc * (BNt / 2) + j * 16 + lr;
        if (MODE == 2) {
            float bv = b0[ncol];
#pragma unroll
            for (int i = 0; i < FM; i++) {
                int mbase = m0 + wr * (BMt / 2) + i * 16 + r0;
#pragma unroll
                for (int r = 0; r < 4; r++)
                    ((float*)C0)[(size_t)(mbase + r) * N + ncol] = acc[i][j][r] + bv;
            }
        } else {
            int sel = n0 >> 10;                    // block-uniform
            const float* bp = sel == 0 ? b0 : (sel == 1 ? b1 : b2);
            int nc = ncol & 1023;
            float bv = bp[nc];
            int hh = nc >> 6, dk = nc & 63;
            ushort_t* Co = (ushort_t*)(sel == 0 ? C0 : (sel == 1 ? C1 : C2));
#pragma unroll
            for (int i = 0; i < FM; i++) {
                int mbase = m0 + wr * (BMt / 2) + i * 16 + r0;
                int bb = mbase >> 11, ss = mbase & 2047;
                if (sel == 2) {
                    ushort4 pk;
                    pk.x = f2bf(acc[i][j][0] + bv);
                    pk.y = f2bf(acc[i][j][1] + bv);
                    pk.z = f2bf(acc[i][j][2] + bv);
                    pk.w = f2bf(acc[i][j][3] + bv);
                    size_t idx = ((size_t)(bb * NH + hh) * DK + dk) * S_LEN + ss;
                    *(ushort4*)&Co[idx] = pk;
                } else {
#pragma unroll
                    for (int r = 0; r < 4; r++) {
                        size_t idx = ((size_t)(bb * NH + hh) * S_LEN + (ss + r)) * DK + dk;
                        Co[idx] = f2bf(acc[i][j][r] + bv);
                    }
                }
            }
        }
    }
}

// ---------------- Flash attention (causal, equal-length chunks) ----------------
// Grid (bh=32, y=40) = 1280 blocks = 5/CU. Chunk lengths 7..18: j=0..12
// bundled in pairs, j=13..17 single, j=18..31 halved. Residency classes
// (y%8) each sum exactly 66 tile-units. KT: 0/1 = split chunk, 9 = single,
// 10+jb = bundle {JT, jb}. Inner machinery = round-13 verified (unchanged).
#define CSC 0.1803368801f   // 0.125 * log2(e)

__device__ const unsigned char JTAB[40] = {
    17,16,15,30,31,31,13,27,
    24,18,18,19,19,20,26,28,
    12,14,28,29,29,30,27,25,
    11,10, 9, 8, 7,25,23,26,
     6,20,21,21,22,22,23,24};
__device__ const unsigned char KTAB[40] = {
     9, 9, 9, 0, 0, 1, 9, 1,
     0, 1, 0, 0, 1, 1, 0, 1,
    10, 9, 0, 0, 1, 1, 0, 1,
    11,12,13,14,15, 0, 0, 1,
     9, 0, 0, 1, 1, 0, 1, 1};

__global__ __launch_bounds__(256, 5) void attn_fwd(const ushort_t* __restrict__ Q,
                                                   const ushort_t* __restrict__ K,
                                                   const ushort_t* __restrict__ Vt,
                                                   ushort_t* __restrict__ Oa,
                                                   float2* __restrict__ ml,
                                                   float* __restrict__ Pd) {
    __shared__ ushort_t Ks[2][64 * 64];
    __shared__ ushort_t Vs[2][64 * 64];

    int tid = threadIdx.x;
    int lane = tid & 63;
    int w = tid >> 6;
    int bh = blockIdx.x;           // 0..31
    int yy = blockIdx.y;           // 0..39
    int JT = JTAB[yy];
    int KT = KTAB[yy];
    int nseg = (KT >= 10) ? 2 : 1;
    size_t base = (size_t)bh * S_LEN * DK;

    int lr = lane & 15;
    int lk = (lane >> 4) * 8;
    int g16 = (lane >> 4) * 16;
    int r0 = (lane >> 4) * 4;
    int wq = w * 16 + lr;

    // Hoisted LDS read bases ((n*16+lr)&7 == lr&7)
    int swb = (lr & 7) << 4;
    int swLo = (lr * 128 + (g16 ^ swb)) >> 1;
    int swHi = (lr * 128 + ((64 + g16) ^ swb)) >> 1;

    int sr = tid >> 3;            // 0..31
    int scb = (tid & 7) * 16;
    int wOff = (sr * 128 + (scb ^ ((sr & 7) << 4))) >> 1;

    const ushort_t* kBase = K  + base + (size_t)sr * DK + ((tid & 7) * 8);
    const ushort_t* vBase = Vt + base + (size_t)sr * S_LEN + ((tid & 7) * 8);
    int b = bh >> 4, h = bh & 15;

    for (int seg = 0; seg < nseg; ++seg) {
        int j = (seg == 0) ? JT : (KT - 10);
        int kk = (KT <= 1) ? KT : 9;
        int nt = j + 1;
        int half = (nt + 1) >> 1;
        int t0 = (kk == 1) ? half : 0;
        int t1 = (kk == 0) ? half : nt;
        int cnt = t1 - t0;
        int off = yy % cnt;
        int q0 = j * 64;

        short8 qf0 = *(const short8*)&Q[base + (size_t)(q0 + wq) * DK + lk];
        short8 qf1 = *(const short8*)&Q[base + (size_t)(q0 + wq) * DK + 32 + lk];

        f32x4 o[4] = {};
        float mrowL = -1e30f, lrow = 0.f;

        int tf = t0 + off;
        {
            const ushort_t* kp = kBase + (size_t)tf * (64 * DK);
            const ushort_t* vp = vBase + (size_t)tf * 64;
            *(uint4*)&Ks[0][wOff]        = *(const uint4*)kp;
            *(uint4*)&Ks[0][wOff + 2048] = *(const uint4*)(kp + 32 * DK);
            *(uint4*)&Vs[0][wOff]        = *(const uint4*)vp;
            *(uint4*)&Vs[0][wOff + 2048] = *(const uint4*)(vp + 32 * S_LEN);
        }
        __syncthreads();

        int t = tf;
        int tpre = (tf == t1 - 1) ? t0 : tf + 1;
        const ushort_t* kPre = kBase + (size_t)tpre * (64 * DK);
        const ushort_t* vPre = vBase + (size_t)tpre * 64;

        int cur = 0;
        for (int s = 0; s < cnt; ++s) {
            bool last = (s == cnt - 1);
            bool diag = (t == j);
            uint4 kr0, kr1, vr0, vr1;
            if (!last) {
                kr0 = *(const uint4*)kPre;
                kr1 = *(const uint4*)(kPre + 32 * DK);
                vr0 = *(const uint4*)vPre;
                vr1 = *(const uint4*)(vPre + 32 * S_LEN);
            }

            f32x4 st[4] = {};
            __builtin_amdgcn_s_setprio(1);
#pragma unroll
            for (int n = 0; n < 4; n++) {
                if (!diag || n <= w) {
                    short8 kf0 = *(const short8*)&Ks[cur][swLo + n * 1024];
                    short8 kf1 = *(const short8*)&Ks[cur][swHi + n * 1024];
                    st[n] = __builtin_amdgcn_mfma_f32_16x16x32_bf16(kf0, qf0, st[n], 0, 0, 0);
                    st[n] = __builtin_amdgcn_mfma_f32_16x16x32_bf16(kf1, qf1, st[n], 0, 0, 0);
                }
            }
            __builtin_amdgcn_s_setprio(0);

            if (diag) {
#pragma unroll
                for (int n = 0; n < 4; n++)
#pragma unroll
                    for (int i = 0; i < 4; i++)
                        if (16 * n + r0 + i > wq) st[n][i] = -1e30f;
            }

            float m0 = fmaxf(fmaxf(fmaxf(st[0][0], st[0][1]), st[0][2]), st[0][3]);
            float m1 = fmaxf(fmaxf(fmaxf(st[1][0], st[1][1]), st[1][2]), st[1][3]);
            float m2 = fmaxf(fmaxf(fmaxf(st[2][0], st[2][1]), st[2][2]), st[2][3]);
            float m3 = fmaxf(fmaxf(fmaxf(st[3][0], st[3][1]), st[3][2]), st[3][3]);
            float mx = fmaxf(fmaxf(fmaxf(m0, m1), m2), m3);
            float mxL = red_max4(mx) * CSC;

            bool skip = __all(mxL <= mrowL + 8.0f);   // T13 defer-max
            float corr = 1.0f;
            float mnewL = mrowL;
            if (!skip) {
                mnewL = fmaxf(mrowL, mxL);
                corr = fexp2(mrowL - mnewL);
                mrowL = mnewL;
            }

            float psum = 0.f;
            uint32_t wp[4][2];
#pragma unroll
            for (int n = 0; n < 4; n++) {
#pragma unroll
                for (int i = 0; i < 4; i++) {
                    float p = fexp2(fmaf(st[n][i], CSC, -mnewL));
                    st[n][i] = p;
                    psum += p;
                }
                wp[n][0] = (uint32_t)bfc(st[n][0]) | ((uint32_t)bfc(st[n][1]) << 16);
                wp[n][1] = (uint32_t)bfc(st[n][2]) | ((uint32_t)bfc(st[n][3]) << 16);
            }
            psum = red_sum4(psum);

            if (skip) {
                lrow += psum;
            } else {
                lrow = lrow * corr + psum;
                float cb[4];
#pragma unroll
                for (int i = 0; i < 4; i++) cb[i] = __shfl(corr, r0 + i);
#pragma unroll
                for (int d = 0; d < 4; d++)
#pragma unroll
                    for (int i = 0; i < 4; i++) o[d][i] *= cb[i];
            }

#pragma unroll
            for (int ks = 0; ks < 2; ks++) {
                if (diag && 32 * ks > w * 16 + 15) continue;
                uint32_t F[4];
                route_p(wp, ks, lane, F);
                union { uint32_t u[4]; short8 s; } pu;
                pu.u[0] = F[0]; pu.u[1] = F[1]; pu.u[2] = F[2]; pu.u[3] = F[3];
                short8 pf = pu.s;
                int vb = (ks ? swHi : swLo);
                __builtin_amdgcn_s_setprio(1);
#pragma unroll
                for (int d = 0; d < 4; d++) {
                    short8 vf = *(const short8*)&Vs[cur][vb + d * 1024];
                    o[d] = __builtin_amdgcn_mfma_f32_16x16x32_bf16(pf, vf, o[d], 0, 0, 0);
                }
                __builtin_amdgcn_s_setprio(0);
            }

            if (!last) {
                *(uint4*)&Ks[cur ^ 1][wOff]        = kr0;
                *(uint4*)&Ks[cur ^ 1][wOff + 2048] = kr1;
                *(uint4*)&Vs[cur ^ 1][wOff]        = vr0;
                *(uint4*)&Vs[cur ^ 1][wOff + 2048] = vr1;
            }
            __syncthreads();
            cur ^= 1;

            t = tpre;
            bool wrap = (tpre == t1 - 1);
            tpre = wrap ? t0 : tpre + 1;
            kPre += wrap ? -(ptrdiff_t)(cnt - 1) * (64 * DK) : (ptrdiff_t)(64 * DK);
            vPre += wrap ? -(ptrdiff_t)(cnt - 1) * 64 : (ptrdiff_t)64;
        }

        // segment epilogue
        if (kk == 9) {
            float lb[4];
#pragma unroll
            for (int i = 0; i < 4; i++) lb[i] = frcp(__shfl(lrow, r0 + i));
#pragma unroll
            for (int d = 0; d < 4; d++)
#pragma unroll
                for (int i = 0; i < 4; i++) {
                    int qq = q0 + w * 16 + r0 + i;
                    int dk = d * 16 + lr;
                    size_t idx = ((size_t)(b * S_LEN + qq)) * D_DIM + h * DK + dk;
                    Oa[idx] = bfc(o[d][i] * lb[i]);
                }
        } else {
            int jj = j - 18;               // split j's are 18..31
            if (kk == 0) {
#pragma unroll
                for (int d = 0; d < 4; d++)
#pragma unroll
                    for (int i = 0; i < 4; i++) {
                        int qq = q0 + w * 16 + r0 + i;
                        int dk = d * 16 + lr;
                        size_t idx = ((size_t)(b * S_LEN + qq)) * D_DIM + h * DK + dk;
                        Oa[idx] = bfc(o[d][i]);
                    }
            } else {
#pragma unroll
                for (int d = 0; d < 4; d++)
#pragma unroll
                    for (int i = 0; i < 4; i++) {
                        int rloc = w * 16 + r0 + i;
                        Pd[((size_t)(bh * NSPL + jj) * 64 + rloc) * 64 + d * 16 + lr] = o[d][i];
                    }
            }
            if (lane < 16) {
                int row = w * 16 + lane;
                ml[(size_t)kk * MLSTR + (bh * NSPL + jj) * 64 + row] = make_float2(mrowL, lrow);
            }
        }
    }
}

// ---------------- merge of split-tile partials (j = 18..31) ----------------
__global__ __launch_bounds__(256) void attn_merge(const float2* __restrict__ ml,
                                                  const float* __restrict__ Pd,
                                                  ushort_t* __restrict__ Oa) {
    int bh = blockIdx.x;           // 0..31
    int jj = blockIdx.y;           // 0..13 -> j = jj+18
    int tid = threadIdx.x;
    int r = tid >> 2;              // row 0..63
    int q = (tid & 3) * 16;        // dk start
    int b = bh >> 4, h = bh & 15;
    int row = (jj + 18) * 64 + r;
    float2 a = ml[(bh * NSPL + jj) * 64 + r];
    float2 c = ml[MLSTR + (bh * NSPL + jj) * 64 + r];
    float M = fmaxf(a.x, c.x);
    float w0 = fexp2(a.x - M), w1 = fexp2(c.x - M);
    float rc = frcp(a.y * w0 + c.y * w1);
    size_t ob = ((size_t)(b * S_LEN + row)) * D_DIM + h * DK + q;
    const float* p1 = &Pd[((size_t)(bh * NSPL + jj) * 64 + r) * 64 + q];
#pragma unroll
    for (int i = 0; i < 4; i++) {
        ushort4 o0 = *(const ushort4*)&Oa[ob + i * 4];
        float4 o1 = *(const float4*)&p1[i * 4];
        ushort4 res;
        res.x = bfc((bf2f(o0.x) * w0 + o1.x * w1) * rc);
        res.y = bfc((bf2f(o0.y) * w0 + o1.y * w1) * rc);
        res.z = bfc((bf2f(o0.z) * w0 + o1.z * w1) * rc);
        res.w = bfc((bf2f(o0.w) * w0 + o1.w * w1) * rc);
        *(ushort4*)&Oa[ob + i * 4] = res;
    }
}

// ---------------- launch ----------------
extern "C" void kernel_launch(void* const* d_in, const int* in_sizes, int n_in,
                              void* d_out, int out_size, void* d_ws, size_t ws_size,
                              hipStream_t stream) {
    const float* X  = (const float*)d_in[0];
    const float* Wq = (const float*)d_in[1];
    const float* bq = (const float*)d_in[2];
    const float* Wk = (const float*)d_in[3];
    const float* bk = (const float*)d_in[4];
    const float* Wv = (const float*)d_in[5];
    const float* bv = (const float*)d_in[6];
    const float* Wo = (const float*)d_in[7];
    const float* bo = (const float*)d_in[8];
    float* out = (float*)d_out;

    char* ws = (char*)d_ws;
    ushort_t* Xb    = (ushort_t*)ws;                        // 8 MiB [M,D] bf16 (later: attn out)
    ushort_t* Wqkvb = (ushort_t*)(ws + (8u  << 20));        // 6 MiB; dead after QKV gemm
    float2*   mlbuf = (float2*)(ws + (8u  << 20));          // 448 KiB (over dead Wqkvb)
    ushort_t* Qb    = (ushort_t*)(ws + (14u << 20));        // 8 MiB [b,h,s,dk]
    ushort_t* Kb    = (ushort_t*)(ws + (22u << 20));        // 8 MiB [b,h,s,dk]
    ushort_t* Vtb   = (ushort_t*)(ws + (30u << 20));        // 8 MiB [b,h,dk,s]
    ushort_t* Wob   = Wqkvb;                                // reuse after merge
    ushort_t* Ab    = Xb;                                   // attn out reuses X slot
    float*    Pd    = out;                                  // chunk1 partials scratch (dead until Wo gemm)

    const int M = M_ROWS;
    int nX4 = (M * D_DIM) / 4;
    int nW4 = (D_DIM * D_DIM) / 4;

    cvt_bf16<<<2048, 256, 0, stream>>>(X, Xb, nX4);
    cvt_w3<<<2048, 256, 0, stream>>>(Wq, Wk, Wv, Wqkvb);

    // fused QKV: 32 x 24 = 768 blocks (3/CU)
    gemm_bt<3, 128, 128><<<dim3((M / 128) * (3072 / 128)), 256, 0, stream>>>(
        Xb, Wqkvb, bq, bk, bv, Qb, Kb, Vtb, M, 3072, D_DIM);

    // attn: 32 x 40 = 1280 chunk-blocks = 5/CU, lengths 7..18, class sums 66
    dim3 agrid(BATCH * NH, 40);
    attn_fwd<<<agrid, 256, 0, stream>>>(Qb, Kb, Vtb, Ab, mlbuf, Pd);

    // merge split-tile partials (j=18..31)
    attn_merge<<<dim3(BATCH * NH, NSPL), 256, 0, stream>>>(mlbuf, Pd, Ab);

    cvt_bf16<<<2048, 256, 0, stream>>>(Wo, Wob, nW4);   // after merge (overlays mlbuf)

    // Wo gemm: 64x128 tiles -> 512 blocks (2/CU); overwrites all of d_out
    gemm_bt<2, 64, 128><<<dim3((M / 64) * (D_DIM / 128)), 256, 0, stream>>>(
        Ab, Wob, bo, bo, bo, out, out, out, M, D_DIM, D_DIM);
}

// Round 17
// 116.729 us; speedup vs baseline: 1.3187x; 1.0456x over previous
//
#include <hip/hip_runtime.h>
#include <hip/hip_bf16.h>
#include <cstdint>

typedef __attribute__((ext_vector_type(8))) short short8;
typedef __attribute__((ext_vector_type(4))) float f32x4;
typedef __attribute__((ext_vector_type(2))) unsigned int uint2v;
typedef unsigned short ushort_t;

#define S_LEN 2048
#define D_DIM 1024
#define NH 16
#define DK 64
#define BATCH 2
#define M_ROWS (BATCH * S_LEN)   // 4096
#define BK 32

__device__ inline ushort_t f2bf(float f) {
    union { float f; uint32_t u; } v; v.f = f;
    uint32_t r = v.u + 0x7fffu + ((v.u >> 16) & 1u);  // RNE
    return (ushort_t)(r >> 16);
}

__device__ __forceinline__ ushort_t bfc(float f) {
    __hip_bfloat16 h = __float2bfloat16(f);          // HW cvt path
    return __builtin_bit_cast(ushort_t, h);
}

__device__ __forceinline__ float bf2f(ushort_t u) {
    return __uint_as_float(((uint32_t)u) << 16);
}

// HW transcendentals (OCML exp2f/div are multi-instruction without fast-math)
__device__ __forceinline__ float fexp2(float x) {
#if __has_builtin(__builtin_amdgcn_exp2f)
    return __builtin_amdgcn_exp2f(x);
#else
    return exp2f(x);
#endif
}
__device__ __forceinline__ float frcp(float x) {
#if __has_builtin(__builtin_amdgcn_rcpf)
    return __builtin_amdgcn_rcpf(x);
#else
    return 1.0f / x;
#endif
}

__device__ __forceinline__ void glds16(const ushort_t* g, ushort_t* l) {
    __builtin_amdgcn_global_load_lds(
        (const __attribute__((address_space(1))) uint32_t*)g,
        (__attribute__((address_space(3))) uint32_t*)l,
        16, 0, 0);
}

#if __has_builtin(__builtin_amdgcn_permlane16_swap) && __has_builtin(__builtin_amdgcn_permlane32_swap)
#define HAS_PLSWAP 1
#else
#define HAS_PLSWAP 0
#endif

// cross-lane reduce over the 4 16-lane groups (lanes l, l^16, l^32, l^48)
__device__ __forceinline__ float red_max4(float x) {
#if HAS_PLSWAP
    uint2v a = __builtin_amdgcn_permlane16_swap(__float_as_uint(x), __float_as_uint(x), false, false);
    float y = fmaxf(__uint_as_float(a.x), __uint_as_float(a.y));
    uint2v b = __builtin_amdgcn_permlane32_swap(__float_as_uint(y), __float_as_uint(y), false, false);
    return fmaxf(__uint_as_float(b.x), __uint_as_float(b.y));
#else
    x = fmaxf(x, __shfl_xor(x, 16));
    return fmaxf(x, __shfl_xor(x, 32));
#endif
}
__device__ __forceinline__ float red_sum4(float x) {
#if HAS_PLSWAP
    uint2v a = __builtin_amdgcn_permlane16_swap(__float_as_uint(x), __float_as_uint(x), false, false);
    float y = __uint_as_float(a.x) + __uint_as_float(a.y);
    uint2v b = __builtin_amdgcn_permlane32_swap(__float_as_uint(y), __float_as_uint(y), false, false);
    return __uint_as_float(b.x) + __uint_as_float(b.y);
#else
    x += __shfl_xor(x, 16);
    return x + __shfl_xor(x, 32);
#endif
}

// T12 route: build PV A-frag words F[0..3] for k-slice ks from packed P words
// wp[n][h] (kv = 16n + 4*(lane>>4) + 2h + {0,1}, q = lane&15).
__device__ __forceinline__ void route_p(const uint32_t wp[4][2], int ks, int lane, uint32_t F[4]) {
#if HAS_PLSWAP
    uint32_t U0 = wp[2 * ks][0],     U1 = wp[2 * ks][1];
    uint32_t V0 = wp[2 * ks + 1][0], V1 = wp[2 * ks + 1][1];
    uint2v t, pa0, pa1, pb0, pb1;
    t = __builtin_amdgcn_permlane32_swap(U0, U0, false, false);
    pa0 = __builtin_amdgcn_permlane16_swap(U0, t.y, false, false);
    t = __builtin_amdgcn_permlane32_swap(U1, U1, false, false);
    pa1 = __builtin_amdgcn_permlane16_swap(U1, t.y, false, false);
    t = __builtin_amdgcn_permlane32_swap(V0, V0, false, false);
    pb0 = __builtin_amdgcn_permlane16_swap(t.x, V0, false, false);
    t = __builtin_amdgcn_permlane32_swap(V1, V1, false, false);
    pb1 = __builtin_amdgcn_permlane16_swap(t.x, V1, false, false);
    bool lo = lane < 32;
    F[0] = lo ? pa0.x : pb0.x;
    F[1] = lo ? pa1.x : pb1.x;
    F[2] = lo ? pa0.y : pb0.y;
    F[3] = lo ? pa1.y : pb1.y;
#else
    int q = lane & 15, g = lane >> 4;
#pragma unroll
    for (int m = 0; m < 4; m++) {
        int src = 16 * (2 * (g & 1) + (m >> 1)) + q;
        uint32_t xa = (uint32_t)__shfl((int)wp[2 * ks][m & 1], src);
        uint32_t xb = (uint32_t)__shfl((int)wp[2 * ks + 1][m & 1], src);
        F[m] = (g < 2) ? xa : xb;
    }
#endif
}

// ---------------- fused fp32 -> bf16 converts (X + Wq/Wk/Wv in one launch) ----------------
__global__ void cvt_all(const float* __restrict__ X,
                        const float* __restrict__ wq, const float* __restrict__ wk,
                        const float* __restrict__ wv,
                        ushort_t* __restrict__ Xb, ushort_t* __restrict__ wqkv) {
    const int nX4 = (M_ROWS * D_DIM) / 4;     // 2^20
    const int seg = (D_DIM * D_DIM) / 4;      // 2^18
    const int total = nX4 + 3 * seg;          // 1835008
    int i = blockIdx.x * blockDim.x + threadIdx.x;
    int stride = gridDim.x * blockDim.x;
    for (int idx = i; idx < total; idx += stride) {
        const float* src;
        ushort4* dst;
        if (idx < nX4) {
            src = X + (size_t)idx * 4;
            dst = (ushort4*)Xb + idx;
        } else {
            int rem = idx - nX4;
            int sel = rem >> 18;
            int id = rem & (seg - 1);
            const float* w = sel == 0 ? wq : (sel == 1 ? wk : wv);
            src = w + (size_t)id * 4;
            dst = (ushort4*)wqkv + sel * seg + id;
        }
        float4 v = *(const float4*)src;
        ushort4 o;
        o.x = f2bf(v.x); o.y = f2bf(v.y); o.z = f2bf(v.z); o.w = f2bf(v.w);
        *dst = o;
    }
}

// plain convert (Wo)
__global__ void cvt_bf16(const float* __restrict__ in, ushort_t* __restrict__ out, int n4) {
    int i = blockIdx.x * blockDim.x + threadIdx.x;
    int stride = gridDim.x * blockDim.x;
    for (int idx = i; idx < n4; idx += stride) {
        float4 v = ((const float4*)in)[idx];
        ushort4 o;
        o.x = f2bf(v.x); o.y = f2bf(v.y); o.z = f2bf(v.z); o.w = f2bf(v.w);
        ((ushort4*)out)[idx] = o;
    }
}

// ---------------- GEMM: C = A[M,K] * Bw[N,K]^T + bias ----------------
// ROUND-13 VERIFIED VERSION. T1 XCD remap + single-barrier dbuf staging.
template<int MODE, int BMt, int BNt>
__global__ __launch_bounds__(256, 3) void gemm_bt(const ushort_t* __restrict__ A,
                                                  const ushort_t* __restrict__ Bw,
                                                  const float* __restrict__ b0,
                                                  const float* __restrict__ b1,
                                                  const float* __restrict__ b2,
                                                  void* __restrict__ C0,
                                                  void* __restrict__ C1,
                                                  void* __restrict__ C2,
                                                  int M, int N, int K) {
    constexpr int FM = BMt / 32, FN = BNt / 32;
    constexpr int ACH = BMt / 64, BCH = BNt / 64;
    __shared__ ushort_t As[2][BMt * BK];
    __shared__ ushort_t Bs[2][BNt * BK];
    int tid = threadIdx.x;
    int lane = tid & 63;
    int w = tid >> 6;
    int wr = w >> 1, wc = w & 1;
    int nwg = gridDim.x;
    int bx = (blockIdx.x & 7) * (nwg >> 3) + (blockIdx.x >> 3);
    int ntile = N / BNt;
    int m0 = (bx / ntile) * BMt;
    int n0 = (bx % ntile) * BNt;
    int lr = lane & 15;
    int lk = (lane >> 4) * 8;
    int srow = lane >> 2;            // 0..15
    int scol = (lane & 3) * 8;

    auto stage = [&](int b, int kt) {
#pragma unroll
        for (int c = 0; c < ACH; c++)
            glds16(&A[(size_t)(m0 + w * (BMt / 4) + c * 16 + srow) * K + kt + scol],
                   &As[b][(w * (BMt / 4) + c * 16) * BK]);
#pragma unroll
        for (int c = 0; c < BCH; c++)
            glds16(&Bw[(size_t)(n0 + w * (BNt / 4) + c * 16 + srow) * K + kt + scol],
                   &Bs[b][(w * (BNt / 4) + c * 16) * BK]);
    };

    f32x4 acc[FM][FN] = {};

    stage(0, 0);
    __syncthreads();                 // drain prologue glds
    int cur = 0;
    for (int kt = 0; kt < K; kt += BK) {
        if (kt + BK < K) stage(cur ^ 1, kt + BK);   // next tile in flight

        short8 af[FM], bf[FN];
#pragma unroll
        for (int f = 0; f < FM; f++)
            af[f] = *(const short8*)&As[cur][(wr * (BMt / 2) + f * 16 + lr) * BK + lk];
#pragma unroll
        for (int f = 0; f < FN; f++)
            bf[f] = *(const short8*)&Bs[cur][(wc * (BNt / 2) + f * 16 + lr) * BK + lk];
#pragma unroll
        for (int i = 0; i < FM; i++)
#pragma unroll
            for (int j = 0; j < FN; j++)
                acc[i][j] = __builtin_amdgcn_mfma_f32_16x16x32_bf16(af[i], bf[j], acc[i][j], 0, 0, 0);

        __syncthreads();             // drains this iter's glds + ds_reads
        cur ^= 1;
    }

    int r0 = (lane >> 4) * 4;
#pragma unroll
    for (int j = 0; j < FN; j++) {
        int ncol = n0 + wc * (BNt / 2) + j * 16 + lr;
        if (MODE == 2) {
            float bv = b0[ncol];
#pragma unroll
            for (int i = 0; i < FM; i++) {
                int mbase = m0 + wr * (BMt / 2) + i * 16 + r0;
#pragma unroll
                for (int r = 0; r < 4; r++)
                    ((float*)C0)[(size_t)(mbase + r) * N + ncol] = acc[i][j][r] + bv;
            }
        } else {
            int sel = n0 >> 10;                    // block-uniform
            const float* bp = sel == 0 ? b0 : (sel == 1 ? b1 : b2);
            int nc = ncol & 1023;
            float bv = bp[nc];
            int hh = nc >> 6, dk = nc & 63;
            ushort_t* Co = (ushort_t*)(sel == 0 ? C0 : (sel == 1 ? C1 : C2));
#pragma unroll
            for (int i = 0; i < FM; i++) {
                int mbase = m0 + wr * (BMt / 2) + i * 16 + r0;
                int bb = mbase >> 11, ss = mbase & 2047;
                if (sel == 2) {
                    ushort4 pk;
                    pk.x = f2bf(acc[i][j][0] + bv);
                    pk.y = f2bf(acc[i][j][1] + bv);
                    pk.z = f2bf(acc[i][j][2] + bv);
                    pk.w = f2bf(acc[i][j][3] + bv);
                    size_t idx = ((size_t)(bb * NH + hh) * DK + dk) * S_LEN + ss;
                    *(ushort4*)&Co[idx] = pk;
                } else {
#pragma unroll
                    for (int r = 0; r < 4; r++) {
                        size_t idx = ((size_t)(bb * NH + hh) * S_LEN + (ss + r)) * DK + dk;
                        Co[idx] = f2bf(acc[i][j][r] + bv);
                    }
                }
            }
        }
    }
}

// ---------------- Flash attention (causal, kv-split, full-residency) ----------------
// ROUND-14 VERIFIED VERSION (best measured: 53.3 us). Grid (bh=32, y=40) =
// 1280 blocks = 5/CU; splits j=24..31; snake-balanced classes sum 66;
// staggered tile order; hoisted swizzle bases; strength-reduced pointers.
#define CSC 0.1803368801f   // 0.125 * log2(e)

__device__ const unsigned char JTAB[40] = {
    23,22,21,20,19,18,17,16,
    31,31,30,28,29,26,27,15,
    24,25,30,28,29,27,26,14,
    24,11, 9,10, 8,25,12,13,
     0, 1, 2, 4, 6, 5, 7, 3};
__device__ const unsigned char KTAB[40] = {
     9, 9, 9, 9, 9, 9, 9, 9,
     0, 1, 0, 0, 0, 0, 1, 9,
     0, 0, 1, 1, 1, 0, 1, 9,
     1, 9, 9, 9, 9, 1, 9, 9,
     9, 9, 9, 9, 9, 9, 9, 9};

__global__ __launch_bounds__(256, 5) void attn_fwd(const ushort_t* __restrict__ Q,
                                                   const ushort_t* __restrict__ K,
                                                   const ushort_t* __restrict__ Vt,
                                                   ushort_t* __restrict__ Oa,
                                                   float2* __restrict__ ml,
                                                   float* __restrict__ Pd) {
    __shared__ ushort_t Ks[2][64 * 64];
    __shared__ ushort_t Vs[2][64 * 64];

    int tid = threadIdx.x;
    int lane = tid & 63;
    int w = tid >> 6;
    int bh = blockIdx.x;           // 0..31
    int yy = blockIdx.y;           // 0..39
    int j = JTAB[yy];
    int kk = KTAB[yy];             // 0/1 = split chunk, 9 = single
    int nt = j + 1;
    int half = (nt + 1) >> 1;
    int t0 = (kk == 1) ? half : 0;
    int t1 = (kk == 0) ? half : nt;
    int cnt = t1 - t0;
    int off = yy % cnt;            // per-block stagger (same-CU mates differ)
    size_t base = (size_t)bh * S_LEN * DK;
    int q0 = j * 64;

    int lr = lane & 15;
    int lk = (lane >> 4) * 8;
    int g16 = (lane >> 4) * 16;    // byte col of fragment k-slice
    int r0 = (lane >> 4) * 4;
    int wq = w * 16 + lr;          // this lane's q row (within tile)

    // Hoisted LDS read bases ((n*16+lr)&7 == lr&7)
    int swb = (lr & 7) << 4;
    int swLo = (lr * 128 + (g16 ^ swb)) >> 1;
    int swHi = (lr * 128 + ((64 + g16) ^ swb)) >> 1;

    // Q fragment (16 rows per wave)
    short8 qf0 = *(const short8*)&Q[base + (size_t)(q0 + wq) * DK + lk];
    short8 qf1 = *(const short8*)&Q[base + (size_t)(q0 + wq) * DK + 32 + lk];

    f32x4 o[4] = {};
    float mrowL = -1e30f, lrow = 0.f;

    int sr = tid >> 3;            // 0..31
    int scb = (tid & 7) * 16;     // byte col
    int wOff = (sr * 128 + (scb ^ ((sr & 7) << 4))) >> 1;

    const ushort_t* kBase = K  + base + (size_t)sr * DK + ((tid & 7) * 8);
    const ushort_t* vBase = Vt + base + (size_t)sr * S_LEN + ((tid & 7) * 8);

    // prologue: stage first (staggered) tile into buf 0 (swizzled)
    int tf = t0 + off;
    {
        const ushort_t* kp = kBase + (size_t)tf * (64 * DK);
        const ushort_t* vp = vBase + (size_t)tf * 64;
        *(uint4*)&Ks[0][wOff]        = *(const uint4*)kp;
        *(uint4*)&Ks[0][wOff + 2048] = *(const uint4*)(kp + 32 * DK);
        *(uint4*)&Vs[0][wOff]        = *(const uint4*)vp;
        *(uint4*)&Vs[0][wOff + 2048] = *(const uint4*)(vp + 32 * S_LEN);
    }
    __syncthreads();

    int t = tf;                                    // current tile
    int tpre = (tf == t1 - 1) ? t0 : tf + 1;       // prefetch target
    const ushort_t* kPre = kBase + (size_t)tpre * (64 * DK);
    const ushort_t* vPre = vBase + (size_t)tpre * 64;

    int cur = 0;
    for (int s = 0; s < cnt; ++s) {
        bool last = (s == cnt - 1);
        bool diag = (t == j);
        uint4 kr0, kr1, vr0, vr1;
        if (!last) {
            kr0 = *(const uint4*)kPre;
            kr1 = *(const uint4*)(kPre + 32 * DK);
            vr0 = *(const uint4*)vPre;
            vr1 = *(const uint4*)(vPre + 32 * S_LEN);
        }

        // swapped QK^T: st rows = kv (regs), cols = q (lanes)
        f32x4 st[4] = {};
        __builtin_amdgcn_s_setprio(1);
#pragma unroll
        for (int n = 0; n < 4; n++) {
            if (!diag || n <= w) {   // skip fully-masked kv frags on diagonal
                short8 kf0 = *(const short8*)&Ks[cur][swLo + n * 1024];
                short8 kf1 = *(const short8*)&Ks[cur][swHi + n * 1024];
                st[n] = __builtin_amdgcn_mfma_f32_16x16x32_bf16(kf0, qf0, st[n], 0, 0, 0);
                st[n] = __builtin_amdgcn_mfma_f32_16x16x32_bf16(kf1, qf1, st[n], 0, 0, 0);
            }
        }
        __builtin_amdgcn_s_setprio(0);

        if (diag) {   // causal mask within diagonal tile
#pragma unroll
            for (int n = 0; n < 4; n++)
#pragma unroll
                for (int i = 0; i < 4; i++)
                    if (16 * n + r0 + i > wq) st[n][i] = -1e30f;
        }

        // per-lane softmax (q = lr), reduce across 4 lane-groups
        float m0 = fmaxf(fmaxf(fmaxf(st[0][0], st[0][1]), st[0][2]), st[0][3]);
        float m1 = fmaxf(fmaxf(fmaxf(st[1][0], st[1][1]), st[1][2]), st[1][3]);
        float m2 = fmaxf(fmaxf(fmaxf(st[2][0], st[2][1]), st[2][2]), st[2][3]);
        float m3 = fmaxf(fmaxf(fmaxf(st[3][0], st[3][1]), st[3][2]), st[3][3]);
        float mx = fmaxf(fmaxf(fmaxf(m0, m1), m2), m3);
        float mxL = red_max4(mx) * CSC;

        bool skip = __all(mxL <= mrowL + 8.0f);   // T13 defer-max
        float corr = 1.0f;
        float mnewL = mrowL;
        if (!skip) {
            mnewL = fmaxf(mrowL, mxL);
            corr = fexp2(mrowL - mnewL);
            mrowL = mnewL;
        }

        float psum = 0.f;
        uint32_t wp[4][2];
#pragma unroll
        for (int n = 0; n < 4; n++) {
#pragma unroll
            for (int i = 0; i < 4; i++) {
                float p = fexp2(fmaf(st[n][i], CSC, -mnewL));
                st[n][i] = p;
                psum += p;
            }
            wp[n][0] = (uint32_t)bfc(st[n][0]) | ((uint32_t)bfc(st[n][1]) << 16);
            wp[n][1] = (uint32_t)bfc(st[n][2]) | ((uint32_t)bfc(st[n][3]) << 16);
        }
        psum = red_sum4(psum);

        if (skip) {
            lrow += psum;
        } else {
            lrow = lrow * corr + psum;
            float cb[4];
#pragma unroll
            for (int i = 0; i < 4; i++) cb[i] = __shfl(corr, r0 + i);
#pragma unroll
            for (int d = 0; d < 4; d++)
#pragma unroll
                for (int i = 0; i < 4; i++) o[d][i] *= cb[i];
        }

        // PV: O += P V, P frags routed in-register
#pragma unroll
        for (int ks = 0; ks < 2; ks++) {
            if (diag && 32 * ks > w * 16 + 15) continue;  // slice fully masked
            uint32_t F[4];
            route_p(wp, ks, lane, F);
            union { uint32_t u[4]; short8 s; } pu;
            pu.u[0] = F[0]; pu.u[1] = F[1]; pu.u[2] = F[2]; pu.u[3] = F[3];
            short8 pf = pu.s;
            int vb = (ks ? swHi : swLo);              // compile-time select
            __builtin_amdgcn_s_setprio(1);
#pragma unroll
            for (int d = 0; d < 4; d++) {
                short8 vf = *(const short8*)&Vs[cur][vb + d * 1024];
                o[d] = __builtin_amdgcn_mfma_f32_16x16x32_bf16(pf, vf, o[d], 0, 0, 0);
            }
            __builtin_amdgcn_s_setprio(0);
        }

        if (!last) {
            *(uint4*)&Ks[cur ^ 1][wOff]        = kr0;
            *(uint4*)&Ks[cur ^ 1][wOff + 2048] = kr1;
            *(uint4*)&Vs[cur ^ 1][wOff]        = vr0;
            *(uint4*)&Vs[cur ^ 1][wOff + 2048] = vr1;
        }
        __syncthreads();
        cur ^= 1;

        // advance current tile + prefetch pointers (incremental, wrap-adjusted)
        t = tpre;
        bool wrap = (tpre == t1 - 1);
        tpre = wrap ? t0 : tpre + 1;
        kPre += wrap ? -(ptrdiff_t)(cnt - 1) * (64 * DK) : (ptrdiff_t)(64 * DK);
        vPre += wrap ? -(ptrdiff_t)(cnt - 1) * 64 : (ptrdiff_t)64;
    }

    // epilogue
    int b = bh >> 4, h = bh & 15;
    if (kk == 9) {
        // single chunk: normalize and write final bf16
        float lb[4];
#pragma unroll
        for (int i = 0; i < 4; i++) lb[i] = frcp(__shfl(lrow, r0 + i));
#pragma unroll
        for (int d = 0; d < 4; d++)
#pragma unroll
            for (int i = 0; i < 4; i++) {
                int qq = q0 + w * 16 + r0 + i;
                int dk = d * 16 + lr;
                size_t idx = ((size_t)(b * S_LEN + qq)) * D_DIM + h * DK + dk;
                Oa[idx] = bfc(o[d][i] * lb[i]);
            }
    } else {
        int jj = j - 24;               // split j's are 24..31
        if (kk == 0) {
            // chunk0 partial: unnormalized bf16 into the final O slot
#pragma unroll
            for (int d = 0; d < 4; d++)
#pragma unroll
                for (int i = 0; i < 4; i++) {
                    int qq = q0 + w * 16 + r0 + i;
                    int dk = d * 16 + lr;
                    size_t idx = ((size_t)(b * S_LEN + qq)) * D_DIM + h * DK + dk;
                    Oa[idx] = bfc(o[d][i]);
                }
        } else {
            // chunk1 partial: f32 into Pd scratch (d_out)
#pragma unroll
            for (int d = 0; d < 4; d++)
#pragma unroll
                for (int i = 0; i < 4; i++) {
                    int rloc = w * 16 + r0 + i;
                    Pd[((size_t)(bh * 8 + jj) * 64 + rloc) * 64 + d * 16 + lr] = o[d][i];
                }
        }
        if (lane < 16) {
            int row = w * 16 + lane;   // lanes 0..15 hold rows (q=lr) stats
            ml[(size_t)kk * 16384 + (bh * 8 + jj) * 64 + row] = make_float2(mrowL, lrow);
        }
    }
}

// ---------------- merge of split-tile partials (j = 24..31) ----------------
__global__ __launch_bounds__(256) void attn_merge(const float2* __restrict__ ml,
                                                  const float* __restrict__ Pd,
                                                  ushort_t* __restrict__ Oa) {
    int bh = blockIdx.x;           // 0..31
    int jj = blockIdx.y;           // 0..7 -> j = jj+24
    int tid = threadIdx.x;
    int r = tid >> 2;              // row 0..63
    int q = (tid & 3) * 16;        // dk start
    int b = bh >> 4, h = bh & 15;
    int row = (jj + 24) * 64 + r;
    float2 a = ml[(bh * 8 + jj) * 64 + r];
    float2 c = ml[16384 + (bh * 8 + jj) * 64 + r];
    float M = fmaxf(a.x, c.x);
    float w0 = fexp2(a.x - M), w1 = fexp2(c.x - M);
    float rc = frcp(a.y * w0 + c.y * w1);
    size_t ob = ((size_t)(b * S_LEN + row)) * D_DIM + h * DK + q;
    const float* p1 = &Pd[((size_t)(bh * 8 + jj) * 64 + r) * 64 + q];
#pragma unroll
    for (int i = 0; i < 4; i++) {
        ushort4 o0 = *(const ushort4*)&Oa[ob + i * 4];
        float4 o1 = *(const float4*)&p1[i * 4];
        ushort4 res;
        res.x = bfc((bf2f(o0.x) * w0 + o1.x * w1) * rc);
        res.y = bfc((bf2f(o0.y) * w0 + o1.y * w1) * rc);
        res.z = bfc((bf2f(o0.z) * w0 + o1.z * w1) * rc);
        res.w = bfc((bf2f(o0.w) * w0 + o1.w * w1) * rc);
        *(ushort4*)&Oa[ob + i * 4] = res;
    }
}

// ---------------- launch ----------------
extern "C" void kernel_launch(void* const* d_in, const int* in_sizes, int n_in,
                              void* d_out, int out_size, void* d_ws, size_t ws_size,
                              hipStream_t stream) {
    const float* X  = (const float*)d_in[0];
    const float* Wq = (const float*)d_in[1];
    const float* bq = (const float*)d_in[2];
    const float* Wk = (const float*)d_in[3];
    const float* bk = (const float*)d_in[4];
    const float* Wv = (const float*)d_in[5];
    const float* bv = (const float*)d_in[6];
    const float* Wo = (const float*)d_in[7];
    const float* bo = (const float*)d_in[8];
    float* out = (float*)d_out;

    char* ws = (char*)d_ws;
    ushort_t* Xb    = (ushort_t*)ws;                        // 8 MiB [M,D] bf16 (later: attn out)
    ushort_t* Wqkvb = (ushort_t*)(ws + (8u  << 20));        // 6 MiB; dead after QKV gemm
    float2*   mlbuf = (float2*)(ws + (8u  << 20));          // 256 KiB (over dead Wqkvb)
    ushort_t* Qb    = (ushort_t*)(ws + (14u << 20));        // 8 MiB [b,h,s,dk]
    ushort_t* Kb    = (ushort_t*)(ws + (22u << 20));        // 8 MiB [b,h,s,dk]
    ushort_t* Vtb   = (ushort_t*)(ws + (30u << 20));        // 8 MiB [b,h,dk,s]
    ushort_t* Wob   = Wqkvb;                                // reuse after merge
    ushort_t* Ab    = Xb;                                   // attn out reuses X slot
    float*    Pd    = out;                                  // chunk1 partials scratch (dead until Wo gemm)

    const int M = M_ROWS;
    int nW4 = (D_DIM * D_DIM) / 4;

    // fused converts: X + Wq/Wk/Wv in one launch
    cvt_all<<<2048, 256, 0, stream>>>(X, Wq, Wk, Wv, Xb, Wqkvb);

    // fused QKV: 32 x 24 = 768 blocks (3/CU)
    gemm_bt<3, 128, 128><<<dim3((M / 128) * (3072 / 128)), 256, 0, stream>>>(
        Xb, Wqkvb, bq, bk, bv, Qb, Kb, Vtb, M, 3072, D_DIM);

    // attn: 32 x 40 = 1280 chunk-blocks = exactly 5/CU, all co-resident
    dim3 agrid(BATCH * NH, 40);
    attn_fwd<<<agrid, 256, 0, stream>>>(Qb, Kb, Vtb, Ab, mlbuf, Pd);

    // merge split-tile partials (j=24..31)
    attn_merge<<<dim3(BATCH * NH, 8), 256, 0, stream>>>(mlbuf, Pd, Ab);

    cvt_bf16<<<1024, 256, 0, stream>>>(Wo, Wob, nW4);   // after merge (overlays mlbuf)

    // Wo gemm: 64x128 tiles -> 512 blocks (2/CU); overwrites all of d_out
    gemm_bt<2, 64, 128><<<dim3((M / 64) * (D_DIM / 128)), 256, 0, stream>>>(
        Ab, Wob, bo, bo, bo, out, out, out, M, D_DIM, D_DIM);
}

// Round 18
// 115.753 us; speedup vs baseline: 1.3298x; 1.0084x over previous
//
#include <hip/hip_runtime.h>
#include <hip/hip_bf16.h>
#include <cstdint>

typedef __attribute__((ext_vector_type(8))) short short8;
typedef __attribute__((ext_vector_type(4))) float f32x4;
typedef __attribute__((ext_vector_type(2))) unsigned int uint2v;
typedef unsigned short ushort_t;

#define S_LEN 2048
#define D_DIM 1024
#define NH 16
#define DK 64
#define BATCH 2
#define M_ROWS (BATCH * S_LEN)   // 4096
#define BK 32

__device__ inline ushort_t f2bf(float f) {
    union { float f; uint32_t u; } v; v.f = f;
    uint32_t r = v.u + 0x7fffu + ((v.u >> 16) & 1u);  // RNE
    return (ushort_t)(r >> 16);
}

__device__ __forceinline__ ushort_t bfc(float f) {
    __hip_bfloat16 h = __float2bfloat16(f);          // HW cvt path
    return __builtin_bit_cast(ushort_t, h);
}

__device__ __forceinline__ float bf2f(ushort_t u) {
    return __uint_as_float(((uint32_t)u) << 16);
}

// HW transcendentals (OCML exp2f/div are multi-instruction without fast-math)
__device__ __forceinline__ float fexp2(float x) {
#if __has_builtin(__builtin_amdgcn_exp2f)
    return __builtin_amdgcn_exp2f(x);
#else
    return exp2f(x);
#endif
}
__device__ __forceinline__ float frcp(float x) {
#if __has_builtin(__builtin_amdgcn_rcpf)
    return __builtin_amdgcn_rcpf(x);
#else
    return 1.0f / x;
#endif
}

__device__ __forceinline__ void glds16(const ushort_t* g, ushort_t* l) {
    __builtin_amdgcn_global_load_lds(
        (const __attribute__((address_space(1))) uint32_t*)g,
        (__attribute__((address_space(3))) uint32_t*)l,
        16, 0, 0);
}

#if __has_builtin(__builtin_amdgcn_permlane16_swap) && __has_builtin(__builtin_amdgcn_permlane32_swap)
#define HAS_PLSWAP 1
#else
#define HAS_PLSWAP 0
#endif

// cross-lane reduce over the 4 16-lane groups (lanes l, l^16, l^32, l^48)
__device__ __forceinline__ float red_max4(float x) {
#if HAS_PLSWAP
    uint2v a = __builtin_amdgcn_permlane16_swap(__float_as_uint(x), __float_as_uint(x), false, false);
    float y = fmaxf(__uint_as_float(a.x), __uint_as_float(a.y));
    uint2v b = __builtin_amdgcn_permlane32_swap(__float_as_uint(y), __float_as_uint(y), false, false);
    return fmaxf(__uint_as_float(b.x), __uint_as_float(b.y));
#else
    x = fmaxf(x, __shfl_xor(x, 16));
    return fmaxf(x, __shfl_xor(x, 32));
#endif
}
__device__ __forceinline__ float red_sum4(float x) {
#if HAS_PLSWAP
    uint2v a = __builtin_amdgcn_permlane16_swap(__float_as_uint(x), __float_as_uint(x), false, false);
    float y = __uint_as_float(a.x) + __uint_as_float(a.y);
    uint2v b = __builtin_amdgcn_permlane32_swap(__float_as_uint(y), __float_as_uint(y), false, false);
    return __uint_as_float(b.x) + __uint_as_float(b.y);
#else
    x += __shfl_xor(x, 16);
    return x + __shfl_xor(x, 32);
#endif
}

// T12 route: build PV A-frag words F[0..3] for k-slice ks from packed P words
// wp[n][h] (kv = 16n + 4*(lane>>4) + 2h + {0,1}, q = lane&15).
__device__ __forceinline__ void route_p(const uint32_t wp[4][2], int ks, int lane, uint32_t F[4]) {
#if HAS_PLSWAP
    uint32_t U0 = wp[2 * ks][0],     U1 = wp[2 * ks][1];
    uint32_t V0 = wp[2 * ks + 1][0], V1 = wp[2 * ks + 1][1];
    uint2v t, pa0, pa1, pb0, pb1;
    t = __builtin_amdgcn_permlane32_swap(U0, U0, false, false);
    pa0 = __builtin_amdgcn_permlane16_swap(U0, t.y, false, false);
    t = __builtin_amdgcn_permlane32_swap(U1, U1, false, false);
    pa1 = __builtin_amdgcn_permlane16_swap(U1, t.y, false, false);
    t = __builtin_amdgcn_permlane32_swap(V0, V0, false, false);
    pb0 = __builtin_amdgcn_permlane16_swap(t.x, V0, false, false);
    t = __builtin_amdgcn_permlane32_swap(V1, V1, false, false);
    pb1 = __builtin_amdgcn_permlane16_swap(t.x, V1, false, false);
    bool lo = lane < 32;
    F[0] = lo ? pa0.x : pb0.x;
    F[1] = lo ? pa1.x : pb1.x;
    F[2] = lo ? pa0.y : pb0.y;
    F[3] = lo ? pa1.y : pb1.y;
#else
    int q = lane & 15, g = lane >> 4;
#pragma unroll
    for (int m = 0; m < 4; m++) {
        int src = 16 * (2 * (g & 1) + (m >> 1)) + q;
        uint32_t xa = (uint32_t)__shfl((int)wp[2 * ks][m & 1], src);
        uint32_t xb = (uint32_t)__shfl((int)wp[2 * ks + 1][m & 1], src);
        F[m] = (g < 2) ? xa : xb;
    }
#endif
}

// ---------------- fused fp32 -> bf16 converts (X + Wq/Wk/Wv in one launch) ----------------
__global__ void cvt_all(const float* __restrict__ X,
                        const float* __restrict__ wq, const float* __restrict__ wk,
                        const float* __restrict__ wv,
                        ushort_t* __restrict__ Xb, ushort_t* __restrict__ wqkv) {
    const int nX4 = (M_ROWS * D_DIM) / 4;     // 2^20
    const int seg = (D_DIM * D_DIM) / 4;      // 2^18
    const int total = nX4 + 3 * seg;          // 1835008
    int i = blockIdx.x * blockDim.x + threadIdx.x;
    int stride = gridDim.x * blockDim.x;
    for (int idx = i; idx < total; idx += stride) {
        const float* src;
        ushort4* dst;
        if (idx < nX4) {
            src = X + (size_t)idx * 4;
            dst = (ushort4*)Xb + idx;
        } else {
            int rem = idx - nX4;
            int sel = rem >> 18;
            int id = rem & (seg - 1);
            const float* w = sel == 0 ? wq : (sel == 1 ? wk : wv);
            src = w + (size_t)id * 4;
            dst = (ushort4*)wqkv + sel * seg + id;
        }
        float4 v = *(const float4*)src;
        ushort4 o;
        o.x = f2bf(v.x); o.y = f2bf(v.y); o.z = f2bf(v.z); o.w = f2bf(v.w);
        *dst = o;
    }
}

// plain convert (Wo)
__global__ void cvt_bf16(const float* __restrict__ in, ushort_t* __restrict__ out, int n4) {
    int i = blockIdx.x * blockDim.x + threadIdx.x;
    int stride = gridDim.x * blockDim.x;
    for (int idx = i; idx < n4; idx += stride) {
        float4 v = ((const float4*)in)[idx];
        ushort4 o;
        o.x = f2bf(v.x); o.y = f2bf(v.y); o.z = f2bf(v.z); o.w = f2bf(v.w);
        ((ushort4*)out)[idx] = o;
    }
}

// ---------------- GEMM: C = A[M,K] * Bw[N,K]^T + bias ----------------
// Round-13 structure + NEW bank-conflict fix (rule #21 pattern): the LDS dest
// of global_load_lds is lane-linear and cannot be swizzled/padded, so we
// pre-swizzle the GLOBAL source per lane: staging lane l loads col-block
// (l&3)^(srow&3). LDS (r,sb) then holds global (r, sb^(r&3)). Fragment reads
// XOR the same: slice' = (lane>>4)^(lr&3) -- a lane constant (all fragment
// rows are lr mod 16, so row&3 == lr&3). 8-way ds_read conflict -> 4-way.
template<int MODE, int BMt, int BNt>
__global__ __launch_bounds__(256, 3) void gemm_bt(const ushort_t* __restrict__ A,
                                                  const ushort_t* __restrict__ Bw,
                                                  const float* __restrict__ b0,
                                                  const float* __restrict__ b1,
                                                  const float* __restrict__ b2,
                                                  void* __restrict__ C0,
                                                  void* __restrict__ C1,
                                                  void* __restrict__ C2,
                                                  int M, int N, int K) {
    constexpr int FM = BMt / 32, FN = BNt / 32;
    constexpr int ACH = BMt / 64, BCH = BNt / 64;
    __shared__ ushort_t As[2][BMt * BK];
    __shared__ ushort_t Bs[2][BNt * BK];
    int tid = threadIdx.x;
    int lane = tid & 63;
    int w = tid >> 6;
    int wr = w >> 1, wc = w & 1;
    int nwg = gridDim.x;
    int bx = (blockIdx.x & 7) * (nwg >> 3) + (blockIdx.x >> 3);
    int ntile = N / BNt;
    int m0 = (bx / ntile) * BMt;
    int n0 = (bx % ntile) * BNt;
    int lr = lane & 15;
    // swizzled k-slice read base: (lane>>4) ^ (lr&3), in elements
    int lk = (((lane >> 4) ^ (lr & 3)) & 3) * 8;
    int srow = lane >> 2;            // 0..15
    // swizzled staging source col-block: (lane&3) ^ (srow&3)
    int scol = (((lane & 3) ^ (srow & 3)) & 3) * 8;

    auto stage = [&](int b, int kt) {
#pragma unroll
        for (int c = 0; c < ACH; c++)
            glds16(&A[(size_t)(m0 + w * (BMt / 4) + c * 16 + srow) * K + kt + scol],
                   &As[b][(w * (BMt / 4) + c * 16) * BK]);
#pragma unroll
        for (int c = 0; c < BCH; c++)
            glds16(&Bw[(size_t)(n0 + w * (BNt / 4) + c * 16 + srow) * K + kt + scol],
                   &Bs[b][(w * (BNt / 4) + c * 16) * BK]);
    };

    f32x4 acc[FM][FN] = {};

    stage(0, 0);
    __syncthreads();                 // drain prologue glds
    int cur = 0;
    for (int kt = 0; kt < K; kt += BK) {
        if (kt + BK < K) stage(cur ^ 1, kt + BK);   // next tile in flight

        short8 af[FM], bf[FN];
#pragma unroll
        for (int f = 0; f < FM; f++)
            af[f] = *(const short8*)&As[cur][(wr * (BMt / 2) + f * 16 + lr) * BK + lk];
#pragma unroll
        for (int f = 0; f < FN; f++)
            bf[f] = *(const short8*)&Bs[cur][(wc * (BNt / 2) + f * 16 + lr) * BK + lk];
#pragma unroll
        for (int i = 0; i < FM; i++)
#pragma unroll
            for (int j = 0; j < FN; j++)
                acc[i][j] = __builtin_amdgcn_mfma_f32_16x16x32_bf16(af[i], bf[j], acc[i][j], 0, 0, 0);

        __syncthreads();             // drains this iter's glds + ds_reads
        cur ^= 1;
    }

    int r0 = (lane >> 4) * 4;
#pragma unroll
    for (int j = 0; j < FN; j++) {
        int ncol = n0 + wc * (BNt / 2) + j * 16 + lr;
        if (MODE == 2) {
            float bv = b0[ncol];
#pragma unroll
            for (int i = 0; i < FM; i++) {
                int mbase = m0 + wr * (BMt / 2) + i * 16 + r0;
#pragma unroll
                for (int r = 0; r < 4; r++)
                    ((float*)C0)[(size_t)(mbase + r) * N + ncol] = acc[i][j][r] + bv;
            }
        } else {
            int sel = n0 >> 10;                    // block-uniform
            const float* bp = sel == 0 ? b0 : (sel == 1 ? b1 : b2);
            int nc = ncol & 1023;
            float bv = bp[nc];
            int hh = nc >> 6, dk = nc & 63;
            ushort_t* Co = (ushort_t*)(sel == 0 ? C0 : (sel == 1 ? C1 : C2));
#pragma unroll
            for (int i = 0; i < FM; i++) {
                int mbase = m0 + wr * (BMt / 2) + i * 16 + r0;
                int bb = mbase >> 11, ss = mbase & 2047;
                if (sel == 2) {
                    ushort4 pk;
                    pk.x = f2bf(acc[i][j][0] + bv);
                    pk.y = f2bf(acc[i][j][1] + bv);
                    pk.z = f2bf(acc[i][j][2] + bv);
                    pk.w = f2bf(acc[i][j][3] + bv);
                    size_t idx = ((size_t)(bb * NH + hh) * DK + dk) * S_LEN + ss;
                    *(ushort4*)&Co[idx] = pk;
                } else {
#pragma unroll
                    for (int r = 0; r < 4; r++) {
                        size_t idx = ((size_t)(bb * NH + hh) * S_LEN + (ss + r)) * DK + dk;
                        Co[idx] = f2bf(acc[i][j][r] + bv);
                    }
                }
            }
        }
    }
}

// ---------------- Flash attention (causal, kv-split, full-residency) ----------------
// ROUND-14/17 VERIFIED VERSION (best measured: 52.6 us) -- byte-frozen.
#define CSC 0.1803368801f   // 0.125 * log2(e)

__device__ const unsigned char JTAB[40] = {
    23,22,21,20,19,18,17,16,
    31,31,30,28,29,26,27,15,
    24,25,30,28,29,27,26,14,
    24,11, 9,10, 8,25,12,13,
     0, 1, 2, 4, 6, 5, 7, 3};
__device__ const unsigned char KTAB[40] = {
     9, 9, 9, 9, 9, 9, 9, 9,
     0, 1, 0, 0, 0, 0, 1, 9,
     0, 0, 1, 1, 1, 0, 1, 9,
     1, 9, 9, 9, 9, 1, 9, 9,
     9, 9, 9, 9, 9, 9, 9, 9};

__global__ __launch_bounds__(256, 5) void attn_fwd(const ushort_t* __restrict__ Q,
                                                   const ushort_t* __restrict__ K,
                                                   const ushort_t* __restrict__ Vt,
                                                   ushort_t* __restrict__ Oa,
                                                   float2* __restrict__ ml,
                                                   float* __restrict__ Pd) {
    __shared__ ushort_t Ks[2][64 * 64];
    __shared__ ushort_t Vs[2][64 * 64];

    int tid = threadIdx.x;
    int lane = tid & 63;
    int w = tid >> 6;
    int bh = blockIdx.x;           // 0..31
    int yy = blockIdx.y;           // 0..39
    int j = JTAB[yy];
    int kk = KTAB[yy];             // 0/1 = split chunk, 9 = single
    int nt = j + 1;
    int half = (nt + 1) >> 1;
    int t0 = (kk == 1) ? half : 0;
    int t1 = (kk == 0) ? half : nt;
    int cnt = t1 - t0;
    int off = yy % cnt;            // per-block stagger (same-CU mates differ)
    size_t base = (size_t)bh * S_LEN * DK;
    int q0 = j * 64;

    int lr = lane & 15;
    int lk = (lane >> 4) * 8;
    int g16 = (lane >> 4) * 16;    // byte col of fragment k-slice
    int r0 = (lane >> 4) * 4;
    int wq = w * 16 + lr;          // this lane's q row (within tile)

    // Hoisted LDS read bases ((n*16+lr)&7 == lr&7)
    int swb = (lr & 7) << 4;
    int swLo = (lr * 128 + (g16 ^ swb)) >> 1;
    int swHi = (lr * 128 + ((64 + g16) ^ swb)) >> 1;

    // Q fragment (16 rows per wave)
    short8 qf0 = *(const short8*)&Q[base + (size_t)(q0 + wq) * DK + lk];
    short8 qf1 = *(const short8*)&Q[base + (size_t)(q0 + wq) * DK + 32 + lk];

    f32x4 o[4] = {};
    float mrowL = -1e30f, lrow = 0.f;

    int sr = tid >> 3;            // 0..31
    int scb = (tid & 7) * 16;     // byte col
    int wOff = (sr * 128 + (scb ^ ((sr & 7) << 4))) >> 1;

    const ushort_t* kBase = K  + base + (size_t)sr * DK + ((tid & 7) * 8);
    const ushort_t* vBase = Vt + base + (size_t)sr * S_LEN + ((tid & 7) * 8);

    // prologue: stage first (staggered) tile into buf 0 (swizzled)
    int tf = t0 + off;
    {
        const ushort_t* kp = kBase + (size_t)tf * (64 * DK);
        const ushort_t* vp = vBase + (size_t)tf * 64;
        *(uint4*)&Ks[0][wOff]        = *(const uint4*)kp;
        *(uint4*)&Ks[0][wOff + 2048] = *(const uint4*)(kp + 32 * DK);
        *(uint4*)&Vs[0][wOff]        = *(const uint4*)vp;
        *(uint4*)&Vs[0][wOff + 2048] = *(const uint4*)(vp + 32 * S_LEN);
    }
    __syncthreads();

    int t = tf;                                    // current tile
    int tpre = (tf == t1 - 1) ? t0 : tf + 1;       // prefetch target
    const ushort_t* kPre = kBase + (size_t)tpre * (64 * DK);
    const ushort_t* vPre = vBase + (size_t)tpre * 64;

    int cur = 0;
    for (int s = 0; s < cnt; ++s) {
        bool last = (s == cnt - 1);
        bool diag = (t == j);
        uint4 kr0, kr1, vr0, vr1;
        if (!last) {
            kr0 = *(const uint4*)kPre;
            kr1 = *(const uint4*)(kPre + 32 * DK);
            vr0 = *(const uint4*)vPre;
            vr1 = *(const uint4*)(vPre + 32 * S_LEN);
        }

        // swapped QK^T: st rows = kv (regs), cols = q (lanes)
        f32x4 st[4] = {};
        __builtin_amdgcn_s_setprio(1);
#pragma unroll
        for (int n = 0; n < 4; n++) {
            if (!diag || n <= w) {   // skip fully-masked kv frags on diagonal
                short8 kf0 = *(const short8*)&Ks[cur][swLo + n * 1024];
                short8 kf1 = *(const short8*)&Ks[cur][swHi + n * 1024];
                st[n] = __builtin_amdgcn_mfma_f32_16x16x32_bf16(kf0, qf0, st[n], 0, 0, 0);
                st[n] = __builtin_amdgcn_mfma_f32_16x16x32_bf16(kf1, qf1, st[n], 0, 0, 0);
            }
        }
        __builtin_amdgcn_s_setprio(0);

        if (diag) {   // causal mask within diagonal tile
#pragma unroll
            for (int n = 0; n < 4; n++)
#pragma unroll
                for (int i = 0; i < 4; i++)
                    if (16 * n + r0 + i > wq) st[n][i] = -1e30f;
        }

        // per-lane softmax (q = lr), reduce across 4 lane-groups
        float m0 = fmaxf(fmaxf(fmaxf(st[0][0], st[0][1]), st[0][2]), st[0][3]);
        float m1 = fmaxf(fmaxf(fmaxf(st[1][0], st[1][1]), st[1][2]), st[1][3]);
        float m2 = fmaxf(fmaxf(fmaxf(st[2][0], st[2][1]), st[2][2]), st[2][3]);
        float m3 = fmaxf(fmaxf(fmaxf(st[3][0], st[3][1]), st[3][2]), st[3][3]);
        float mx = fmaxf(fmaxf(fmaxf(m0, m1), m2), m3);
        float mxL = red_max4(mx) * CSC;

        bool skip = __all(mxL <= mrowL + 8.0f);   // T13 defer-max
        float corr = 1.0f;
        float mnewL = mrowL;
        if (!skip) {
            mnewL = fmaxf(mrowL, mxL);
            corr = fexp2(mrowL - mnewL);
            mrowL = mnewL;
        }

        float psum = 0.f;
        uint32_t wp[4][2];
#pragma unroll
        for (int n = 0; n < 4; n++) {
#pragma unroll
            for (int i = 0; i < 4; i++) {
                float p = fexp2(fmaf(st[n][i], CSC, -mnewL));
                st[n][i] = p;
                psum += p;
            }
            wp[n][0] = (uint32_t)bfc(st[n][0]) | ((uint32_t)bfc(st[n][1]) << 16);
            wp[n][1] = (uint32_t)bfc(st[n][2]) | ((uint32_t)bfc(st[n][3]) << 16);
        }
        psum = red_sum4(psum);

        if (skip) {
            lrow += psum;
        } else {
            lrow = lrow * corr + psum;
            float cb[4];
#pragma unroll
            for (int i = 0; i < 4; i++) cb[i] = __shfl(corr, r0 + i);
#pragma unroll
            for (int d = 0; d < 4; d++)
#pragma unroll
                for (int i = 0; i < 4; i++) o[d][i] *= cb[i];
        }

        // PV: O += P V, P frags routed in-register
#pragma unroll
        for (int ks = 0; ks < 2; ks++) {
            if (diag && 32 * ks > w * 16 + 15) continue;  // slice fully masked
            uint32_t F[4];
            route_p(wp, ks, lane, F);
            union { uint32_t u[4]; short8 s; } pu;
            pu.u[0] = F[0]; pu.u[1] = F[1]; pu.u[2] = F[2]; pu.u[3] = F[3];
            short8 pf = pu.s;
            int vb = (ks ? swHi : swLo);              // compile-time select
            __builtin_amdgcn_s_setprio(1);
#pragma unroll
            for (int d = 0; d < 4; d++) {
                short8 vf = *(const short8*)&Vs[cur][vb + d * 1024];
                o[d] = __builtin_amdgcn_mfma_f32_16x16x32_bf16(pf, vf, o[d], 0, 0, 0);
            }
            __builtin_amdgcn_s_setprio(0);
        }

        if (!last) {
            *(uint4*)&Ks[cur ^ 1][wOff]        = kr0;
            *(uint4*)&Ks[cur ^ 1][wOff + 2048] = kr1;
            *(uint4*)&Vs[cur ^ 1][wOff]        = vr0;
            *(uint4*)&Vs[cur ^ 1][wOff + 2048] = vr1;
        }
        __syncthreads();
        cur ^= 1;

        // advance current tile + prefetch pointers (incremental, wrap-adjusted)
        t = tpre;
        bool wrap = (tpre == t1 - 1);
        tpre = wrap ? t0 : tpre + 1;
        kPre += wrap ? -(ptrdiff_t)(cnt - 1) * (64 * DK) : (ptrdiff_t)(64 * DK);
        vPre += wrap ? -(ptrdiff_t)(cnt - 1) * 64 : (ptrdiff_t)64;
    }

    // epilogue
    int b = bh >> 4, h = bh & 15;
    if (kk == 9) {
        // single chunk: normalize and write final bf16
        float lb[4];
#pragma unroll
        for (int i = 0; i < 4; i++) lb[i] = frcp(__shfl(lrow, r0 + i));
#pragma unroll
        for (int d = 0; d < 4; d++)
#pragma unroll
            for (int i = 0; i < 4; i++) {
                int qq = q0 + w * 16 + r0 + i;
                int dk = d * 16 + lr;
                size_t idx = ((size_t)(b * S_LEN + qq)) * D_DIM + h * DK + dk;
                Oa[idx] = bfc(o[d][i] * lb[i]);
            }
    } else {
        int jj = j - 24;               // split j's are 24..31
        if (kk == 0) {
            // chunk0 partial: unnormalized bf16 into the final O slot
#pragma unroll
            for (int d = 0; d < 4; d++)
#pragma unroll
                for (int i = 0; i < 4; i++) {
                    int qq = q0 + w * 16 + r0 + i;
                    int dk = d * 16 + lr;
                    size_t idx = ((size_t)(b * S_LEN + qq)) * D_DIM + h * DK + dk;
                    Oa[idx] = bfc(o[d][i]);
                }
        } else {
            // chunk1 partial: f32 into Pd scratch (d_out)
#pragma unroll
            for (int d = 0; d < 4; d++)
#pragma unroll
                for (int i = 0; i < 4; i++) {
                    int rloc = w * 16 + r0 + i;
                    Pd[((size_t)(bh * 8 + jj) * 64 + rloc) * 64 + d * 16 + lr] = o[d][i];
                }
        }
        if (lane < 16) {
            int row = w * 16 + lane;   // lanes 0..15 hold rows (q=lr) stats
            ml[(size_t)kk * 16384 + (bh * 8 + jj) * 64 + row] = make_float2(mrowL, lrow);
        }
    }
}

// ---------------- merge of split-tile partials (j = 24..31) ----------------
__global__ __launch_bounds__(256) void attn_merge(const float2* __restrict__ ml,
                                                  const float* __restrict__ Pd,
                                                  ushort_t* __restrict__ Oa) {
    int bh = blockIdx.x;           // 0..31
    int jj = blockIdx.y;           // 0..7 -> j = jj+24
    int tid = threadIdx.x;
    int r = tid >> 2;              // row 0..63
    int q = (tid & 3) * 16;        // dk start
    int b = bh >> 4, h = bh & 15;
    int row = (jj + 24) * 64 + r;
    float2 a = ml[(bh * 8 + jj) * 64 + r];
    float2 c = ml[16384 + (bh * 8 + jj) * 64 + r];
    float M = fmaxf(a.x, c.x);
    float w0 = fexp2(a.x - M), w1 = fexp2(c.x - M);
    float rc = frcp(a.y * w0 + c.y * w1);
    size_t ob = ((size_t)(b * S_LEN + row)) * D_DIM + h * DK + q;
    const float* p1 = &Pd[((size_t)(bh * 8 + jj) * 64 + r) * 64 + q];
#pragma unroll
    for (int i = 0; i < 4; i++) {
        ushort4 o0 = *(const ushort4*)&Oa[ob + i * 4];
        float4 o1 = *(const float4*)&p1[i * 4];
        ushort4 res;
        res.x = bfc((bf2f(o0.x) * w0 + o1.x * w1) * rc);
        res.y = bfc((bf2f(o0.y) * w0 + o1.y * w1) * rc);
        res.z = bfc((bf2f(o0.z) * w0 + o1.z * w1) * rc);
        res.w = bfc((bf2f(o0.w) * w0 + o1.w * w1) * rc);
        *(ushort4*)&Oa[ob + i * 4] = res;
    }
}

// ---------------- launch ----------------
extern "C" void kernel_launch(void* const* d_in, const int* in_sizes, int n_in,
                              void* d_out, int out_size, void* d_ws, size_t ws_size,
                              hipStream_t stream) {
    const float* X  = (const float*)d_in[0];
    const float* Wq = (const float*)d_in[1];
    const float* bq = (const float*)d_in[2];
    const float* Wk = (const float*)d_in[3];
    const float* bk = (const float*)d_in[4];
    const float* Wv = (const float*)d_in[5];
    const float* bv = (const float*)d_in[6];
    const float* Wo = (const float*)d_in[7];
    const float* bo = (const float*)d_in[8];
    float* out = (float*)d_out;

    char* ws = (char*)d_ws;
    ushort_t* Xb    = (ushort_t*)ws;                        // 8 MiB [M,D] bf16 (later: attn out)
    ushort_t* Wqkvb = (ushort_t*)(ws + (8u  << 20));        // 6 MiB; dead after QKV gemm
    float2*   mlbuf = (float2*)(ws + (8u  << 20));          // 256 KiB (over dead Wqkvb)
    ushort_t* Qb    = (ushort_t*)(ws + (14u << 20));        // 8 MiB [b,h,s,dk]
    ushort_t* Kb    = (ushort_t*)(ws + (22u << 20));        // 8 MiB [b,h,s,dk]
    ushort_t* Vtb   = (ushort_t*)(ws + (30u << 20));        // 8 MiB [b,h,dk,s]
    ushort_t* Wob   = Wqkvb;                                // reuse after merge
    ushort_t* Ab    = Xb;                                   // attn out reuses X slot
    float*    Pd    = out;                                  // chunk1 partials scratch (dead until Wo gemm)

    const int M = M_ROWS;
    int nW4 = (D_DIM * D_DIM) / 4;

    // fused converts: X + Wq/Wk/Wv in one launch
    cvt_all<<<2048, 256, 0, stream>>>(X, Wq, Wk, Wv, Xb, Wqkvb);

    // fused QKV: 32 x 24 = 768 blocks (3/CU)
    gemm_bt<3, 128, 128><<<dim3((M / 128) * (3072 / 128)), 256, 0, stream>>>(
        Xb, Wqkvb, bq, bk, bv, Qb, Kb, Vtb, M, 3072, D_DIM);

    // attn: 32 x 40 = 1280 chunk-blocks = exactly 5/CU, all co-resident
    dim3 agrid(BATCH * NH, 40);
    attn_fwd<<<agrid, 256, 0, stream>>>(Qb, Kb, Vtb, Ab, mlbuf, Pd);

    // merge split-tile partials (j=24..31)
    attn_merge<<<dim3(BATCH * NH, 8), 256, 0, stream>>>(mlbuf, Pd, Ab);

    cvt_bf16<<<1024, 256, 0, stream>>>(Wo, Wob, nW4);   // after merge (overlays mlbuf)

    // Wo gemm: 64x128 tiles -> 512 blocks (2/CU); overwrites all of d_out
    gemm_bt<2, 64, 128><<<dim3((M / 64) * (D_DIM / 128)), 256, 0, stream>>>(
        Ab, Wob, bo, bo, bo, out, out, out, M, D_DIM, D_DIM);
}